// Round 1
// baseline (936.124 us; speedup 1.0000x reference)
//
#include <hip/hip_runtime.h>

#define DIM 128
#define BN_EPS 1e-5f
#define NB 32  // nodes per gemm block

// ---------------------------------------------------------------------------
// Detect whether edge_index is int64 or int32.
// For little-endian int64 values in [0, 2^31), every odd 32-bit word is 0.
// For int32 random indices in [0, 100000), 256 consecutive odd words cannot
// all be zero (P ~ 1e-1280). Writes flag=1 if int64, 0 if int32.
// ---------------------------------------------------------------------------
__global__ void k_detect(const unsigned int* __restrict__ ei, int* __restrict__ flag) {
    __shared__ int nz;
    if (threadIdx.x == 0) nz = 0;
    __syncthreads();
    unsigned v = ei[2 * threadIdx.x + 1];
    if (v != 0) atomicOr(&nz, 1);
    __syncthreads();
    if (threadIdx.x == 0) *flag = (nz == 0) ? 1 : 0;
}

// ---------------------------------------------------------------------------
// Scatter: agg[dst][d] += x[src][d]; deg[dst] += 1.
// Thread t -> edge e = t>>7, feature d = t&127. Consecutive lanes cover
// consecutive d of one edge -> coalesced x reads and contiguous atomics.
// ---------------------------------------------------------------------------
__global__ void k_scatter(const float* __restrict__ x, const void* __restrict__ ei,
                          const int* __restrict__ flag, float* __restrict__ agg,
                          float* __restrict__ deg, int ne) {
    const int is64 = *flag;
    const long long total = (long long)ne * DIM;
    const long long stride = (long long)gridDim.x * blockDim.x;
    for (long long t = (long long)blockIdx.x * blockDim.x + threadIdx.x; t < total; t += stride) {
        const int e = (int)(t >> 7);
        const int d = (int)(t & 127);
        int src, dst;
        if (is64) {
            const long long* p = (const long long*)ei;
            src = (int)p[e];
            dst = (int)p[ne + e];
        } else {
            const int* p = (const int*)ei;
            src = p[e];
            dst = p[ne + e];
        }
        atomicAdd(&agg[(size_t)dst * DIM + d], x[(size_t)src * DIM + d]);
        if (d == 0) atomicAdd(&deg[dst], 1.0f);
    }
}

// ---------------------------------------------------------------------------
// Fused dual GEMM + bias + relu + BN-stat partial reduction.
// Block = 256 threads handles NB=32 nodes. Thread (g = tid>>7, d = tid&127)
// computes h[n][d] for 16 nodes n in [g*16, g*16+16).
// h written to `hout` (d_out reused as scratch). Per-feature sum/sumsq
// atomically accumulated into ssum/ssq.
// ---------------------------------------------------------------------------
__global__ __launch_bounds__(256) void k_gemm(
    const float* __restrict__ agg, const float* __restrict__ deg,
    const float* __restrict__ x, const float* __restrict__ Wl,
    const float* __restrict__ bl, const float* __restrict__ Wr,
    float* __restrict__ hout, float* __restrict__ ssum, float* __restrict__ ssq,
    int nn)
{
    __shared__ float mean_s[NB][DIM];
    __shared__ float x_s[NB][DIM];
    __shared__ float rdeg_s[NB];
    __shared__ float red_sum[2][DIM];
    __shared__ float red_sq[2][DIM];

    const int tid = threadIdx.x;
    const int base = blockIdx.x * NB;

    if (tid < NB) {
        int node = base + tid;
        rdeg_s[tid] = (node < nn) ? (1.0f / fmaxf(deg[node], 1.0f)) : 1.0f;
    }
    __syncthreads();

    for (int i = tid; i < NB * DIM; i += 256) {
        const int n = i >> 7;
        const int node = base + n;
        float mv = 0.0f, xv = 0.0f;
        if (node < nn) {
            mv = agg[(size_t)base * DIM + i] * rdeg_s[n];
            xv = x[(size_t)base * DIM + i];
        }
        (&mean_s[0][0])[i] = mv;
        (&x_s[0][0])[i] = xv;
    }
    __syncthreads();

    const int d = tid & 127;
    const int g = tid >> 7;
    const int n0 = g * 16;

    float acc[16];
    const float blv = bl[d];
#pragma unroll
    for (int n = 0; n < 16; ++n) acc[n] = blv;

    // mean @ W_l
    for (int k = 0; k < DIM; k += 4) {
        const float w0 = Wl[(k + 0) * DIM + d];
        const float w1 = Wl[(k + 1) * DIM + d];
        const float w2 = Wl[(k + 2) * DIM + d];
        const float w3 = Wl[(k + 3) * DIM + d];
#pragma unroll
        for (int n = 0; n < 16; ++n) {
            const float4 m = *(const float4*)&mean_s[n0 + n][k];
            acc[n] += m.x * w0 + m.y * w1 + m.z * w2 + m.w * w3;
        }
    }
    // x @ W_r
    for (int k = 0; k < DIM; k += 4) {
        const float w0 = Wr[(k + 0) * DIM + d];
        const float w1 = Wr[(k + 1) * DIM + d];
        const float w2 = Wr[(k + 2) * DIM + d];
        const float w3 = Wr[(k + 3) * DIM + d];
#pragma unroll
        for (int n = 0; n < 16; ++n) {
            const float4 m = *(const float4*)&x_s[n0 + n][k];
            acc[n] += m.x * w0 + m.y * w1 + m.z * w2 + m.w * w3;
        }
    }

    // relu + store h + per-thread stats over its 16 nodes
    float s = 0.0f, sq = 0.0f;
#pragma unroll
    for (int n = 0; n < 16; ++n) {
        const int node = base + n0 + n;
        if (node < nn) {
            const float v = fmaxf(acc[n], 0.0f);
            hout[(size_t)node * DIM + d] = v;
            s += v;
            sq += v * v;
        }
    }
    red_sum[g][d] = s;
    red_sq[g][d] = sq;
    __syncthreads();
    if (g == 0) {
        atomicAdd(&ssum[d], red_sum[0][d] + red_sum[1][d]);
        atomicAdd(&ssq[d], red_sq[0][d] + red_sq[1][d]);
    }
}

// ---------------------------------------------------------------------------
// Finalize: out = x + (h - mu) * rsqrt(var+eps) * gamma + beta  (in-place on
// d_out which currently holds h). float4 vectorized.
// ---------------------------------------------------------------------------
__global__ void k_finalize(const float* __restrict__ x, const float* __restrict__ ssum,
                           const float* __restrict__ ssq, const float* __restrict__ gamma,
                           const float* __restrict__ beta, float* __restrict__ out,
                           int nn)
{
    const float invN = 1.0f / (float)nn;
    const int total4 = nn * DIM / 4;
    const int stride = gridDim.x * blockDim.x;
    for (int i = blockIdx.x * blockDim.x + threadIdx.x; i < total4; i += stride) {
        const int dv = i & 31;  // float4 index within feature dim
        const float4 h4 = ((const float4*)out)[i];
        const float4 x4 = ((const float4*)x)[i];
        const float4 s4 = ((const float4*)ssum)[dv];
        const float4 q4 = ((const float4*)ssq)[dv];
        const float4 g4 = ((const float4*)gamma)[dv];
        const float4 b4 = ((const float4*)beta)[dv];
        float4 o;
        {
            const float mu = s4.x * invN;
            const float rs = rsqrtf(q4.x * invN - mu * mu + BN_EPS);
            o.x = x4.x + (h4.x - mu) * rs * g4.x + b4.x;
        }
        {
            const float mu = s4.y * invN;
            const float rs = rsqrtf(q4.y * invN - mu * mu + BN_EPS);
            o.y = x4.y + (h4.y - mu) * rs * g4.y + b4.y;
        }
        {
            const float mu = s4.z * invN;
            const float rs = rsqrtf(q4.z * invN - mu * mu + BN_EPS);
            o.z = x4.z + (h4.z - mu) * rs * g4.z + b4.z;
        }
        {
            const float mu = s4.w * invN;
            const float rs = rsqrtf(q4.w * invN - mu * mu + BN_EPS);
            o.w = x4.w + (h4.w - mu) * rs * g4.w + b4.w;
        }
        ((float4*)out)[i] = o;
    }
}

extern "C" void kernel_launch(void* const* d_in, const int* in_sizes, int n_in,
                              void* d_out, int out_size, void* d_ws, size_t ws_size,
                              hipStream_t stream) {
    const float* x     = (const float*)d_in[0];
    const void*  ei    = d_in[1];
    const float* Wl    = (const float*)d_in[2];
    const float* bl    = (const float*)d_in[3];
    const float* Wr    = (const float*)d_in[4];
    const float* gamma = (const float*)d_in[5];
    const float* beta  = (const float*)d_in[6];
    float* out = (float*)d_out;

    const int nn = in_sizes[0] / DIM;       // 100000
    const int ne = in_sizes[1] / 2;         // 1600000 (element count is dtype-independent)

    float* agg  = (float*)d_ws;
    float* deg  = agg + (size_t)nn * DIM;
    float* ssum = deg + nn;
    float* ssq  = ssum + DIM;
    int*   flag = (int*)(ssq + DIM);

    const size_t zero_bytes = ((size_t)nn * DIM + nn + 2 * DIM) * sizeof(float);
    hipMemsetAsync(d_ws, 0, zero_bytes, stream);

    k_detect<<<1, 256, 0, stream>>>((const unsigned int*)ei, flag);
    k_scatter<<<2048, 256, 0, stream>>>(x, ei, flag, agg, deg, ne);
    k_gemm<<<(nn + NB - 1) / NB, 256, 0, stream>>>(agg, deg, x, Wl, bl, Wr, out, ssum, ssq, nn);
    k_finalize<<<2048, 256, 0, stream>>>(x, ssum, ssq, gamma, beta, out, nn);
}

// Round 2
// 558.833 us; speedup vs baseline: 1.6751x; 1.6751x over previous
//
#include <hip/hip_runtime.h>

#define DIM 128
#define BN_EPS 1e-5f
#define NB 32      // nodes per gemm block
#define SCAN_T 1024

// ---------------------------------------------------------------------------
// Detect int64 vs int32 edge_index (odd 32-bit words of small int64s are 0).
// ---------------------------------------------------------------------------
__global__ void k_detect(const unsigned int* __restrict__ ei, int* __restrict__ flag) {
    __shared__ int nz;
    if (threadIdx.x == 0) nz = 0;
    __syncthreads();
    unsigned v = ei[2 * threadIdx.x + 1];
    if (v != 0) atomicOr(&nz, 1);
    __syncthreads();
    if (threadIdx.x == 0) *flag = (nz == 0) ? 1 : 0;
}

__device__ __forceinline__ void load_edge(const void* ei, int is64, int ne, int e,
                                          int& src, int& dst) {
    if (is64) {
        const long long* p = (const long long*)ei;
        src = (int)p[e];
        dst = (int)p[ne + e];
    } else {
        const int* p = (const int*)ei;
        src = p[e];
        dst = p[ne + e];
    }
}

// ---------------------------------------------------------------------------
// Histogram in-degree: cnt[dst]++ per edge.
// ---------------------------------------------------------------------------
__global__ void k_hist(const void* __restrict__ ei, const int* __restrict__ flag,
                       int* __restrict__ cnt, int ne) {
    const int e = blockIdx.x * blockDim.x + threadIdx.x;
    if (e >= ne) return;
    int src, dst;
    load_edge(ei, *flag, ne, e, src, dst);
    atomicAdd(&cnt[dst], 1);
}

// ---------------------------------------------------------------------------
// Exclusive prefix scan of cnt -> off, in 1024-chunks (Hillis-Steele in LDS).
// ---------------------------------------------------------------------------
__global__ __launch_bounds__(SCAN_T) void k_scan1(const int* __restrict__ cnt,
                                                  int* __restrict__ off,
                                                  int* __restrict__ bsum, int nn) {
    __shared__ int sd[SCAN_T];
    const int tid = threadIdx.x;
    const int i = blockIdx.x * SCAN_T + tid;
    const int v = (i < nn) ? cnt[i] : 0;
    sd[tid] = v;
    __syncthreads();
    for (int ofs = 1; ofs < SCAN_T; ofs <<= 1) {
        const int t = (tid >= ofs) ? sd[tid - ofs] : 0;
        __syncthreads();
        sd[tid] += t;
        __syncthreads();
    }
    if (i < nn) off[i] = sd[tid] - v;           // block-local exclusive
    if (tid == SCAN_T - 1) bsum[blockIdx.x] = sd[tid];
}

__global__ void k_scan2(int* __restrict__ bsum, int nblk) {
    if (threadIdx.x == 0) {
        int run = 0;
        for (int b = 0; b < nblk; ++b) { const int t = bsum[b]; bsum[b] = run; run += t; }
    }
}

__global__ void k_scan3(int* __restrict__ off, const int* __restrict__ bsum,
                        int* __restrict__ cursor, int nn) {
    const int i = blockIdx.x * blockDim.x + threadIdx.x;
    if (i >= nn) return;
    const int o = off[i] + bsum[i >> 10];
    off[i] = o;
    cursor[i] = o;
}

// ---------------------------------------------------------------------------
// Bin: srcbuf[off[dst] ...] = src ids of edges into dst.
// ---------------------------------------------------------------------------
__global__ void k_bin(const void* __restrict__ ei, const int* __restrict__ flag,
                      int* __restrict__ cursor, int* __restrict__ srcbuf, int ne) {
    const int e = blockIdx.x * blockDim.x + threadIdx.x;
    if (e >= ne) return;
    int src, dst;
    load_edge(ei, *flag, ne, e, src, dst);
    const int pos = atomicAdd(&cursor[dst], 1);
    srcbuf[pos] = src;
}

// ---------------------------------------------------------------------------
// Fused: gather-mean aggregation + dual GEMM + bias + relu + BN-stat partials.
// Block = 256 threads (2 teams of 128) handles NB=32 nodes (16 per team).
// Gather: team g, thread d accumulates sum_e x[src_e][d] for its 16 nodes,
// normalizes by degree, stages mean + x rows in LDS. GEMM identical to R1.
// ---------------------------------------------------------------------------
__global__ __launch_bounds__(256) void k_gemm(
    const float* __restrict__ x, const float* __restrict__ Wl,
    const float* __restrict__ bl, const float* __restrict__ Wr,
    const int* __restrict__ off, const int* __restrict__ cnt,
    const int* __restrict__ srcbuf,
    float* __restrict__ hout, float* __restrict__ ssum, float* __restrict__ ssq,
    int nn)
{
    __shared__ float mean_s[NB][DIM];
    __shared__ float x_s[NB][DIM];
    __shared__ float red_sum[2][DIM];
    __shared__ float red_sq[2][DIM];

    const int tid = threadIdx.x;
    const int base = blockIdx.x * NB;
    const int d = tid & 127;
    const int g = tid >> 7;
    const int n0 = g * 16;

    // --- gather-mean phase: each team fills its own 16 rows ---
    for (int n = 0; n < 16; ++n) {
        const int node = base + n0 + n;
        float acc = 0.0f, xv = 0.0f;
        if (node < nn) {
            const int o = off[node];
            const int c = cnt[node];
            int e = 0;
            for (; e + 4 <= c; e += 4) {
                const int s0 = srcbuf[o + e + 0];
                const int s1 = srcbuf[o + e + 1];
                const int s2 = srcbuf[o + e + 2];
                const int s3 = srcbuf[o + e + 3];
                acc += x[(size_t)s0 * DIM + d];
                acc += x[(size_t)s1 * DIM + d];
                acc += x[(size_t)s2 * DIM + d];
                acc += x[(size_t)s3 * DIM + d];
            }
            for (; e < c; ++e) acc += x[(size_t)srcbuf[o + e] * DIM + d];
            acc *= 1.0f / fmaxf((float)c, 1.0f);
            xv = x[(size_t)node * DIM + d];
        }
        mean_s[n0 + n][d] = acc;
        x_s[n0 + n][d] = xv;
    }
    __syncthreads();

    // --- GEMM phase ---
    float acc[16];
    const float blv = bl[d];
#pragma unroll
    for (int n = 0; n < 16; ++n) acc[n] = blv;

    for (int k = 0; k < DIM; k += 4) {
        const float w0 = Wl[(k + 0) * DIM + d];
        const float w1 = Wl[(k + 1) * DIM + d];
        const float w2 = Wl[(k + 2) * DIM + d];
        const float w3 = Wl[(k + 3) * DIM + d];
#pragma unroll
        for (int n = 0; n < 16; ++n) {
            const float4 m = *(const float4*)&mean_s[n0 + n][k];
            acc[n] += m.x * w0 + m.y * w1 + m.z * w2 + m.w * w3;
        }
    }
    for (int k = 0; k < DIM; k += 4) {
        const float w0 = Wr[(k + 0) * DIM + d];
        const float w1 = Wr[(k + 1) * DIM + d];
        const float w2 = Wr[(k + 2) * DIM + d];
        const float w3 = Wr[(k + 3) * DIM + d];
#pragma unroll
        for (int n = 0; n < 16; ++n) {
            const float4 m = *(const float4*)&x_s[n0 + n][k];
            acc[n] += m.x * w0 + m.y * w1 + m.z * w2 + m.w * w3;
        }
    }

    // --- relu + store h + BN-stat partials ---
    float s = 0.0f, sq = 0.0f;
#pragma unroll
    for (int n = 0; n < 16; ++n) {
        const int node = base + n0 + n;
        if (node < nn) {
            const float v = fmaxf(acc[n], 0.0f);
            hout[(size_t)node * DIM + d] = v;
            s += v;
            sq += v * v;
        }
    }
    red_sum[g][d] = s;
    red_sq[g][d] = sq;
    __syncthreads();
    if (g == 0) {
        atomicAdd(&ssum[d], red_sum[0][d] + red_sum[1][d]);
        atomicAdd(&ssq[d], red_sq[0][d] + red_sq[1][d]);
    }
}

// ---------------------------------------------------------------------------
// Finalize: out = x + (h - mu) * rsqrt(var+eps) * gamma + beta (in-place on h).
// ---------------------------------------------------------------------------
__global__ void k_finalize(const float* __restrict__ x, const float* __restrict__ ssum,
                           const float* __restrict__ ssq, const float* __restrict__ gamma,
                           const float* __restrict__ beta, float* __restrict__ out,
                           int nn)
{
    const float invN = 1.0f / (float)nn;
    const int total4 = nn * DIM / 4;
    const int stride = gridDim.x * blockDim.x;
    for (int i = blockIdx.x * blockDim.x + threadIdx.x; i < total4; i += stride) {
        const int dv = i & 31;
        const float4 h4 = ((const float4*)out)[i];
        const float4 x4 = ((const float4*)x)[i];
        const float4 s4 = ((const float4*)ssum)[dv];
        const float4 q4 = ((const float4*)ssq)[dv];
        const float4 g4 = ((const float4*)gamma)[dv];
        const float4 b4 = ((const float4*)beta)[dv];
        float4 o;
        {
            const float mu = s4.x * invN;
            const float rs = rsqrtf(q4.x * invN - mu * mu + BN_EPS);
            o.x = x4.x + (h4.x - mu) * rs * g4.x + b4.x;
        }
        {
            const float mu = s4.y * invN;
            const float rs = rsqrtf(q4.y * invN - mu * mu + BN_EPS);
            o.y = x4.y + (h4.y - mu) * rs * g4.y + b4.y;
        }
        {
            const float mu = s4.z * invN;
            const float rs = rsqrtf(q4.z * invN - mu * mu + BN_EPS);
            o.z = x4.z + (h4.z - mu) * rs * g4.z + b4.z;
        }
        {
            const float mu = s4.w * invN;
            const float rs = rsqrtf(q4.w * invN - mu * mu + BN_EPS);
            o.w = x4.w + (h4.w - mu) * rs * g4.w + b4.w;
        }
        ((float4*)out)[i] = o;
    }
}

extern "C" void kernel_launch(void* const* d_in, const int* in_sizes, int n_in,
                              void* d_out, int out_size, void* d_ws, size_t ws_size,
                              hipStream_t stream) {
    const float* x     = (const float*)d_in[0];
    const void*  ei    = d_in[1];
    const float* Wl    = (const float*)d_in[2];
    const float* bl    = (const float*)d_in[3];
    const float* Wr    = (const float*)d_in[4];
    const float* gamma = (const float*)d_in[5];
    const float* beta  = (const float*)d_in[6];
    float* out = (float*)d_out;

    const int nn = in_sizes[0] / DIM;   // 100000
    const int ne = in_sizes[1] / 2;     // 1600000

    // workspace layout (all 4B types)
    int*   cnt    = (int*)d_ws;
    float* ssum   = (float*)(cnt + nn);
    float* ssq    = ssum + DIM;
    int*   off    = (int*)(ssq + DIM);
    int*   cursor = off + nn;
    int*   bsum   = cursor + nn;
    int*   flag   = bsum + 128;
    int*   srcbuf = flag + 1;

    // zero cnt + ssum + ssq
    hipMemsetAsync(d_ws, 0, (size_t)(nn + 2 * DIM) * sizeof(int), stream);

    k_detect<<<1, 256, 0, stream>>>((const unsigned int*)ei, flag);
    k_hist<<<(ne + 255) / 256, 256, 0, stream>>>(ei, flag, cnt, ne);
    const int nblk = (nn + SCAN_T - 1) / SCAN_T;
    k_scan1<<<nblk, SCAN_T, 0, stream>>>(cnt, off, bsum, nn);
    k_scan2<<<1, 64, 0, stream>>>(bsum, nblk);
    k_scan3<<<(nn + 255) / 256, 256, 0, stream>>>(off, bsum, cursor, nn);
    k_bin<<<(ne + 255) / 256, 256, 0, stream>>>(ei, flag, cursor, srcbuf, ne);
    k_gemm<<<(nn + NB - 1) / NB, 256, 0, stream>>>(x, Wl, bl, Wr, off, cnt, srcbuf,
                                                   out, ssum, ssq, nn);
    k_finalize<<<2048, 256, 0, stream>>>(x, ssum, ssq, gamma, beta, out, nn);
}

// Round 3
// 395.653 us; speedup vs baseline: 2.3660x; 1.4124x over previous
//
#include <hip/hip_runtime.h>

#define DIM 128
#define BN_EPS 1e-5f
#define NB 32
#define SCAN_T 1024

typedef __attribute__((ext_vector_type(8))) short bf16x8;
typedef __attribute__((ext_vector_type(4))) float f32x4;

union B8 { uint4 u; bf16x8 s; };

__device__ __forceinline__ ushort f2bf(float f) {
    unsigned u = __float_as_uint(f);
    u += 0x7fffu + ((u >> 16) & 1u);          // RNE
    return (ushort)(u >> 16);
}
__device__ __forceinline__ float bflo(unsigned v) { return __uint_as_float(v << 16); }
__device__ __forceinline__ float bfhi(unsigned v) { return __uint_as_float(v & 0xffff0000u); }

// ---------------------------------------------------------------------------
// Detect int64 vs int32 edge_index (odd 32-bit words of small int64s are 0).
// ---------------------------------------------------------------------------
__global__ void k_detect(const unsigned int* __restrict__ ei, int* __restrict__ flag) {
    __shared__ int nz;
    if (threadIdx.x == 0) nz = 0;
    __syncthreads();
    unsigned v = ei[2 * threadIdx.x + 1];
    if (v != 0) atomicOr(&nz, 1);
    __syncthreads();
    if (threadIdx.x == 0) *flag = (nz == 0) ? 1 : 0;
}

__device__ __forceinline__ void load_edge(const void* ei, int is64, int ne, int e,
                                          int& src, int& dst) {
    if (is64) {
        const long long* p = (const long long*)ei;
        src = (int)p[e];
        dst = (int)p[ne + e];
    } else {
        const int* p = (const int*)ei;
        src = p[e];
        dst = p[ne + e];
    }
}

// ---------------------------------------------------------------------------
// x (f32) -> bf16 packed, 8 elems/thread.
// ---------------------------------------------------------------------------
__global__ void k_prep_x(const float4* __restrict__ x4, uint4* __restrict__ xb, int n8) {
    const int t = blockIdx.x * blockDim.x + threadIdx.x;
    if (t >= n8) return;
    const float4 a = x4[2 * t], b = x4[2 * t + 1];
    uint4 o;
    o.x = ((unsigned)f2bf(a.y) << 16) | f2bf(a.x);
    o.y = ((unsigned)f2bf(a.w) << 16) | f2bf(a.z);
    o.z = ((unsigned)f2bf(b.y) << 16) | f2bf(b.x);
    o.w = ((unsigned)f2bf(b.w) << 16) | f2bf(b.z);
    xb[t] = o;
}

// ---------------------------------------------------------------------------
// Pack Wl/Wr into per-lane MFMA B-fragment layout:
// wpack[((mat*8 + nt)*4 + kk)*64 + lane] = 8 bf16 of
//   B[k = kk*32 + (lane>>4)*8 + j][n = nt*16 + (lane&15)], j=0..7.
// ---------------------------------------------------------------------------
__global__ void k_prep_w(const float* __restrict__ Wl, const float* __restrict__ Wr,
                         uint4* __restrict__ wpack) {
    const int t = blockIdx.x * blockDim.x + threadIdx.x;
    if (t >= 4096) return;
    const int lane = t & 63, kk = (t >> 6) & 3, nt = (t >> 8) & 7, mat = t >> 11;
    const float* W = mat ? Wr : Wl;
    const int k0 = kk * 32 + (lane >> 4) * 8;
    const int n = nt * 16 + (lane & 15);
    ushort e[8];
#pragma unroll
    for (int j = 0; j < 8; ++j) e[j] = f2bf(W[(size_t)(k0 + j) * DIM + n]);
    uint4 o;
    o.x = ((unsigned)e[1] << 16) | e[0];
    o.y = ((unsigned)e[3] << 16) | e[2];
    o.z = ((unsigned)e[5] << 16) | e[4];
    o.w = ((unsigned)e[7] << 16) | e[6];
    wpack[t] = o;
}

// ---------------------------------------------------------------------------
// Histogram / scan / bin (CSR by dst), unchanged from R2.
// ---------------------------------------------------------------------------
__global__ void k_hist(const void* __restrict__ ei, const int* __restrict__ flag,
                       int* __restrict__ cnt, int ne) {
    const int e = blockIdx.x * blockDim.x + threadIdx.x;
    if (e >= ne) return;
    int src, dst;
    load_edge(ei, *flag, ne, e, src, dst);
    atomicAdd(&cnt[dst], 1);
}

__global__ __launch_bounds__(SCAN_T) void k_scan1(const int* __restrict__ cnt,
                                                  int* __restrict__ off,
                                                  int* __restrict__ bsum, int nn) {
    __shared__ int sd[SCAN_T];
    const int tid = threadIdx.x;
    const int i = blockIdx.x * SCAN_T + tid;
    const int v = (i < nn) ? cnt[i] : 0;
    sd[tid] = v;
    __syncthreads();
    for (int ofs = 1; ofs < SCAN_T; ofs <<= 1) {
        const int t = (tid >= ofs) ? sd[tid - ofs] : 0;
        __syncthreads();
        sd[tid] += t;
        __syncthreads();
    }
    if (i < nn) off[i] = sd[tid] - v;
    if (tid == SCAN_T - 1) bsum[blockIdx.x] = sd[tid];
}

__global__ void k_scan2(int* __restrict__ bsum, int nblk) {
    if (threadIdx.x == 0) {
        int run = 0;
        for (int b = 0; b < nblk; ++b) { const int t = bsum[b]; bsum[b] = run; run += t; }
    }
}

__global__ void k_scan3(int* __restrict__ off, const int* __restrict__ bsum,
                        int* __restrict__ cursor, int nn) {
    const int i = blockIdx.x * blockDim.x + threadIdx.x;
    if (i >= nn) return;
    const int o = off[i] + bsum[i >> 10];
    off[i] = o;
    cursor[i] = o;
}

__global__ void k_bin(const void* __restrict__ ei, const int* __restrict__ flag,
                      int* __restrict__ cursor, int* __restrict__ srcbuf, int ne) {
    const int e = blockIdx.x * blockDim.x + threadIdx.x;
    if (e >= ne) return;
    int src, dst;
    load_edge(ei, *flag, ne, e, src, dst);
    const int pos = atomicAdd(&cursor[dst], 1);
    srcbuf[pos] = src;
}

// ---------------------------------------------------------------------------
// Fused: bf16 gather-mean + dual bf16 MFMA GEMM + bias + relu + BN partials.
// 256 threads = 4 waves; NB=32 nodes. Gather: wave w sums 8 nodes' rows
// (4B bf16x2 per lane = full 256B row per wave-load), writes mean/x to LDS
// with 16B-unit XOR swizzle. MFMA: wave w -> m-tile (w&1), n-tiles
// (w>>1)*4 .. +3; 16x16x32 bf16, K=128, two GEMMs into one accumulator.
// ---------------------------------------------------------------------------
__global__ __launch_bounds__(256, 3) void k_gemm(
    const unsigned* __restrict__ xb, const uint4* __restrict__ wpack,
    const float* __restrict__ bl,
    const int* __restrict__ off, const int* __restrict__ cnt,
    const int* __restrict__ srcbuf,
    float* __restrict__ hout, float* __restrict__ ssum, float* __restrict__ ssq,
    int nn)
{
    __shared__ unsigned mean_u[NB * 64];
    __shared__ unsigned x_u[NB * 64];
    __shared__ float red_sum[2][DIM];
    __shared__ float red_sq[2][DIM];

    const int tid = threadIdx.x;
    const int lane = tid & 63;
    const int w = tid >> 6;
    const int base = blockIdx.x * NB;

    // ---- gather-mean (bf16 in, f32 accum, bf16 out to LDS) ----
    for (int n = 0; n < 8; ++n) {
        const int ln = w * 8 + n;
        const int node = base + ln;
        float aLo = 0.f, aHi = 0.f;
        unsigned xv = 0;
        if (node < nn) {
            xv = xb[(size_t)node * 64 + lane];
            const int o = off[node];
            const int c = cnt[node];
            int e = 0;
            for (; e + 4 <= c; e += 4) {
                const int s0 = srcbuf[o + e], s1 = srcbuf[o + e + 1];
                const int s2 = srcbuf[o + e + 2], s3 = srcbuf[o + e + 3];
                const unsigned v0 = xb[(size_t)s0 * 64 + lane];
                const unsigned v1 = xb[(size_t)s1 * 64 + lane];
                const unsigned v2 = xb[(size_t)s2 * 64 + lane];
                const unsigned v3 = xb[(size_t)s3 * 64 + lane];
                aLo += bflo(v0) + bflo(v1) + bflo(v2) + bflo(v3);
                aHi += bfhi(v0) + bfhi(v1) + bfhi(v2) + bfhi(v3);
            }
            for (; e < c; ++e) {
                const unsigned v = xb[(size_t)srcbuf[o + e] * 64 + lane];
                aLo += bflo(v);
                aHi += bfhi(v);
            }
            const float r = 1.0f / fmaxf((float)c, 1.0f);
            aLo *= r;
            aHi *= r;
        }
        const unsigned mv = ((unsigned)f2bf(aHi) << 16) | f2bf(aLo);
        const int sw = (((lane >> 2) ^ (ln & 15)) << 2) | (lane & 3);
        mean_u[ln * 64 + sw] = mv;
        x_u[ln * 64 + sw] = xv;
    }
    __syncthreads();

    // ---- MFMA phase ----
    const int m = w & 1;
    const int nq = w >> 1;
    const int row16 = lane & 15;
    const int kgrp = lane >> 4;
    const int ln = m * 16 + row16;

    bf16x8 am[4], ax[4];
#pragma unroll
    for (int kk = 0; kk < 4; ++kk) {
        const int unit = (kk * 4 + kgrp) ^ row16;
        B8 va, vb;
        va.u = *(const uint4*)&mean_u[ln * 64 + unit * 4];
        vb.u = *(const uint4*)&x_u[ln * 64 + unit * 4];
        am[kk] = va.s;
        ax[kk] = vb.s;
    }

    f32x4 acc[4];
#pragma unroll
    for (int j = 0; j < 4; ++j) {
        const float bv = bl[(nq * 4 + j) * 16 + row16];
        acc[j] = (f32x4){bv, bv, bv, bv};
    }

#pragma unroll
    for (int j = 0; j < 4; ++j) {
        const int nt = nq * 4 + j;
        const uint4* pl = wpack + (size_t)(nt * 4) * 64 + lane;
        const uint4* pr = wpack + (size_t)((8 + nt) * 4) * 64 + lane;
        B8 wl[4], wr[4];
#pragma unroll
        for (int kk = 0; kk < 4; ++kk) {
            wl[kk].u = pl[kk * 64];
            wr[kk].u = pr[kk * 64];
        }
#pragma unroll
        for (int kk = 0; kk < 4; ++kk)
            acc[j] = __builtin_amdgcn_mfma_f32_16x16x32_bf16(am[kk], wl[kk].s, acc[j], 0, 0, 0);
#pragma unroll
        for (int kk = 0; kk < 4; ++kk)
            acc[j] = __builtin_amdgcn_mfma_f32_16x16x32_bf16(ax[kk], wr[kk].s, acc[j], 0, 0, 0);
    }

    // ---- relu + store h + BN partials ----
#pragma unroll
    for (int j = 0; j < 4; ++j) {
        const int feat = (nq * 4 + j) * 16 + row16;
        float s = 0.f, sq = 0.f;
#pragma unroll
        for (int r = 0; r < 4; ++r) {
            const int node = base + m * 16 + kgrp * 4 + r;
            const float v = fmaxf(acc[j][r], 0.0f);
            if (node < nn) {
                hout[(size_t)node * DIM + feat] = v;
                s += v;
                sq += v * v;
            }
        }
        s += __shfl_xor(s, 16);
        s += __shfl_xor(s, 32);
        sq += __shfl_xor(sq, 16);
        sq += __shfl_xor(sq, 32);
        if (lane < 16) {
            red_sum[m][feat] = s;
            red_sq[m][feat] = sq;
        }
    }
    __syncthreads();
    if (tid < DIM) {
        atomicAdd(&ssum[tid], red_sum[0][tid] + red_sum[1][tid]);
        atomicAdd(&ssq[tid], red_sq[0][tid] + red_sq[1][tid]);
    }
}

// ---------------------------------------------------------------------------
// Finalize: out = x + (h - mu) * rsqrt(var+eps) * gamma + beta (in-place on h).
// ---------------------------------------------------------------------------
__global__ void k_finalize(const float* __restrict__ x, const float* __restrict__ ssum,
                           const float* __restrict__ ssq, const float* __restrict__ gamma,
                           const float* __restrict__ beta, float* __restrict__ out,
                           int nn)
{
    const float invN = 1.0f / (float)nn;
    const int total4 = nn * DIM / 4;
    const int stride = gridDim.x * blockDim.x;
    for (int i = blockIdx.x * blockDim.x + threadIdx.x; i < total4; i += stride) {
        const int dv = i & 31;
        const float4 h4 = ((const float4*)out)[i];
        const float4 x4 = ((const float4*)x)[i];
        const float4 s4 = ((const float4*)ssum)[dv];
        const float4 q4 = ((const float4*)ssq)[dv];
        const float4 g4 = ((const float4*)gamma)[dv];
        const float4 b4 = ((const float4*)beta)[dv];
        float4 o;
        {
            const float mu = s4.x * invN;
            const float rs = rsqrtf(q4.x * invN - mu * mu + BN_EPS);
            o.x = x4.x + (h4.x - mu) * rs * g4.x + b4.x;
        }
        {
            const float mu = s4.y * invN;
            const float rs = rsqrtf(q4.y * invN - mu * mu + BN_EPS);
            o.y = x4.y + (h4.y - mu) * rs * g4.y + b4.y;
        }
        {
            const float mu = s4.z * invN;
            const float rs = rsqrtf(q4.z * invN - mu * mu + BN_EPS);
            o.z = x4.z + (h4.z - mu) * rs * g4.z + b4.z;
        }
        {
            const float mu = s4.w * invN;
            const float rs = rsqrtf(q4.w * invN - mu * mu + BN_EPS);
            o.w = x4.w + (h4.w - mu) * rs * g4.w + b4.w;
        }
        ((float4*)out)[i] = o;
    }
}

extern "C" void kernel_launch(void* const* d_in, const int* in_sizes, int n_in,
                              void* d_out, int out_size, void* d_ws, size_t ws_size,
                              hipStream_t stream) {
    const float* x     = (const float*)d_in[0];
    const void*  ei    = d_in[1];
    const float* Wl    = (const float*)d_in[2];
    const float* bl    = (const float*)d_in[3];
    const float* Wr    = (const float*)d_in[4];
    const float* gamma = (const float*)d_in[5];
    const float* beta  = (const float*)d_in[6];
    float* out = (float*)d_out;

    const int nn = in_sizes[0] / DIM;   // 100000
    const int ne = in_sizes[1] / 2;     // 1600000

    // workspace layout
    int*   cnt    = (int*)d_ws;
    float* ssum   = (float*)(cnt + nn);
    float* ssq    = ssum + DIM;
    int*   off    = (int*)(ssq + DIM);
    int*   cursor = off + nn;
    int*   bsum   = cursor + nn;
    int*   flag   = bsum + 128;
    size_t pos = (size_t)3 * nn + 2 * DIM + 128 + 1;
    pos = (pos + 3) & ~(size_t)3;                       // 16B align
    uint4* wpack  = (uint4*)((int*)d_ws + pos);         // 4096 x uint4
    int*   srcbuf = (int*)(wpack + 4096);
    size_t p2 = (size_t)(srcbuf + ne - (int*)d_ws);
    p2 = (p2 + 3) & ~(size_t)3;
    unsigned* xb  = (unsigned*)((int*)d_ws + p2);       // nn*64 uints (bf16x2)

    hipMemsetAsync(d_ws, 0, (size_t)(nn + 2 * DIM) * sizeof(int), stream);

    k_detect<<<1, 256, 0, stream>>>((const unsigned int*)ei, flag);
    k_prep_x<<<(nn * DIM / 8 + 255) / 256, 256, 0, stream>>>((const float4*)x, (uint4*)xb,
                                                             nn * DIM / 8);
    k_prep_w<<<16, 256, 0, stream>>>(Wl, Wr, wpack);
    k_hist<<<(ne + 255) / 256, 256, 0, stream>>>(ei, flag, cnt, ne);
    const int nblk = (nn + SCAN_T - 1) / SCAN_T;
    k_scan1<<<nblk, SCAN_T, 0, stream>>>(cnt, off, bsum, nn);
    k_scan2<<<1, 64, 0, stream>>>(bsum, nblk);
    k_scan3<<<(nn + 255) / 256, 256, 0, stream>>>(off, bsum, cursor, nn);
    k_bin<<<(ne + 255) / 256, 256, 0, stream>>>(ei, flag, cursor, srcbuf, ne);
    k_gemm<<<(nn + NB - 1) / NB, 256, 0, stream>>>(xb, wpack, bl, off, cnt, srcbuf,
                                                   out, ssum, ssq, nn);
    k_finalize<<<2048, 256, 0, stream>>>(x, ssum, ssq, gamma, beta, out, nn);
}

// Round 4
// 359.696 us; speedup vs baseline: 2.6025x; 1.1000x over previous
//
#include <hip/hip_runtime.h>

#define DIM 128
#define BN_EPS 1e-5f
#define NB 32
#define SCAN_T 1024

typedef __attribute__((ext_vector_type(8))) short bf16x8;
typedef __attribute__((ext_vector_type(4))) float f32x4;

union B8 { uint4 u; bf16x8 s; };

__device__ __forceinline__ ushort f2bf(float f) {
    unsigned u = __float_as_uint(f);
    u += 0x7fffu + ((u >> 16) & 1u);          // RNE
    return (ushort)(u >> 16);
}

// ---------------------------------------------------------------------------
// Fused prep: [0,PB) x->fp8 | [PB,PB+WB) pack W | [PB+WB, +HB) degree hist.
// Hist blocks self-detect int64 vs int32 (256 odd words all zero => int64).
// ---------------------------------------------------------------------------
__global__ void k_prep(const float4* __restrict__ x4, const float* __restrict__ Wl,
                       const float* __restrict__ Wr, const unsigned* __restrict__ eiu,
                       int* __restrict__ cnt, uint2* __restrict__ xf8,
                       uint4* __restrict__ wpack, int nn, int ne, int PB, int WB) {
    __shared__ int nz;
    int b = blockIdx.x;
    const int tid = threadIdx.x;

    if (b < PB) {                       // ---- x -> fp8 (e4m3), 8 elems/thread ----
        const int t = b * 256 + tid;
        const int n8 = nn * DIM / 8;
        if (t < n8) {
            const float4 a = x4[2 * t], c = x4[2 * t + 1];
            int u0 = __builtin_amdgcn_cvt_pk_fp8_f32(a.x, a.y, 0, false);
            u0 = __builtin_amdgcn_cvt_pk_fp8_f32(a.z, a.w, u0, true);
            int u1 = __builtin_amdgcn_cvt_pk_fp8_f32(c.x, c.y, 0, false);
            u1 = __builtin_amdgcn_cvt_pk_fp8_f32(c.z, c.w, u1, true);
            xf8[t] = make_uint2((unsigned)u0, (unsigned)u1);
        }
        return;
    }
    b -= PB;
    if (b < WB) {                       // ---- pack Wl/Wr into MFMA B-fragments ----
        const int t = b * 256 + tid;    // 0..4095
        const int lane = t & 63, kk = (t >> 6) & 3, nt = (t >> 8) & 7, mat = t >> 11;
        const float* W = mat ? Wr : Wl;
        const int k0 = kk * 32 + (lane >> 4) * 8;
        const int n = nt * 16 + (lane & 15);
        ushort e[8];
#pragma unroll
        for (int j = 0; j < 8; ++j) e[j] = f2bf(W[(size_t)(k0 + j) * DIM + n]);
        uint4 o;
        o.x = ((unsigned)e[1] << 16) | e[0];
        o.y = ((unsigned)e[3] << 16) | e[2];
        o.z = ((unsigned)e[5] << 16) | e[4];
        o.w = ((unsigned)e[7] << 16) | e[6];
        wpack[t] = o;
        return;
    }
    b -= WB;                            // ---- degree histogram, self-detect dtype ----
    if (tid == 0) nz = 0;
    __syncthreads();
    const int e = b * 256 + tid;
    const int es = (e < ne) ? e : (ne - 1);
    if (eiu[2 * (size_t)es + 1] != 0) atomicOr(&nz, 1);
    __syncthreads();
    if (e >= ne) return;
    int dst;
    if (nz == 0) dst = (int)((const long long*)eiu)[(size_t)ne + e];
    else         dst = ((const int*)eiu)[(size_t)ne + e];
    atomicAdd(&cnt[dst], 1);
}

// ---------------------------------------------------------------------------
// Exclusive prefix scan of cnt -> off (1024-chunks), block sums, fixup.
// ---------------------------------------------------------------------------
__global__ __launch_bounds__(SCAN_T) void k_scan1(const int* __restrict__ cnt,
                                                  int* __restrict__ off,
                                                  int* __restrict__ bsum, int nn) {
    __shared__ int sd[SCAN_T];
    const int tid = threadIdx.x;
    const int i = blockIdx.x * SCAN_T + tid;
    const int v = (i < nn) ? cnt[i] : 0;
    sd[tid] = v;
    __syncthreads();
    for (int ofs = 1; ofs < SCAN_T; ofs <<= 1) {
        const int t = (tid >= ofs) ? sd[tid - ofs] : 0;
        __syncthreads();
        sd[tid] += t;
        __syncthreads();
    }
    if (i < nn) off[i] = sd[tid] - v;
    if (tid == SCAN_T - 1) bsum[blockIdx.x] = sd[tid];
}

__global__ void k_scan2(int* __restrict__ bsum, int nblk) {
    if (threadIdx.x == 0) {
        int run = 0;
        for (int b = 0; b < nblk; ++b) { const int t = bsum[b]; bsum[b] = run; run += t; }
    }
}

__global__ void k_scan3(int* __restrict__ off, const int* __restrict__ bsum,
                        int* __restrict__ cursor, int nn) {
    const int i = blockIdx.x * blockDim.x + threadIdx.x;
    if (i >= nn) return;
    const int o = off[i] + bsum[i >> 10];
    off[i] = o;
    cursor[i] = o;
}

// ---------------------------------------------------------------------------
// Bin edges into CSR by dst (self-detect dtype).
// ---------------------------------------------------------------------------
__global__ void k_bin(const unsigned* __restrict__ eiu, int* __restrict__ cursor,
                      int* __restrict__ srcbuf, int ne) {
    __shared__ int nz;
    if (threadIdx.x == 0) nz = 0;
    __syncthreads();
    const int e = blockIdx.x * blockDim.x + threadIdx.x;
    const int es = (e < ne) ? e : (ne - 1);
    if (eiu[2 * (size_t)es + 1] != 0) atomicOr(&nz, 1);
    __syncthreads();
    if (e >= ne) return;
    int src, dst;
    if (nz == 0) {
        const long long* p = (const long long*)eiu;
        src = (int)p[e];
        dst = (int)p[(size_t)ne + e];
    } else {
        const int* p = (const int*)eiu;
        src = p[e];
        dst = p[(size_t)ne + e];
    }
    const int pos = atomicAdd(&cursor[dst], 1);
    srcbuf[pos] = src;
}

// ---------------------------------------------------------------------------
// Fused: fp8 gather-mean (4 edges per wave-load) + dual bf16 MFMA GEMM +
// bias + relu + BN partials.
// Gather: lane = g16*16+q; edge slot g16 handles edge e+g16, lane loads 8
// fp8 features [8q,8q+8). Cross-group shfl_xor reduce -> all lanes hold the
// full feature-octet sum. Self row staged from f32 x. LDS 16B-XOR-swizzled.
// ---------------------------------------------------------------------------
__global__ __launch_bounds__(256, 3) void k_gemm(
    const float* __restrict__ x, const uint2* __restrict__ xf8,
    const uint4* __restrict__ wpack, const float* __restrict__ bl,
    const int* __restrict__ off, const int* __restrict__ cnt,
    const int* __restrict__ srcbuf,
    float* __restrict__ hout, float* __restrict__ ssum, float* __restrict__ ssq,
    int nn)
{
    __shared__ uint4 mean4[NB * 16];
    __shared__ uint4 xls4[NB * 16];
    __shared__ float red_sum[2][DIM];
    __shared__ float red_sq[2][DIM];
    unsigned* x_u = (unsigned*)xls4;

    const int tid = threadIdx.x;
    const int lane = tid & 63;
    const int w = tid >> 6;
    const int base = blockIdx.x * NB;
    const int g16 = lane >> 4;
    const int q = lane & 15;

    // ---- gather-mean phase ----
    for (int n = 0; n < 8; ++n) {
        const int ln = w * 8 + n;
        const int node = base + ln;
        float acc[8];
#pragma unroll
        for (int j = 0; j < 8; ++j) acc[j] = 0.f;
        unsigned xw = 0;

        if (node < nn) {                 // wave-uniform branch
            const float2 xv = *(const float2*)(x + (size_t)node * DIM + 2 * lane);
            xw = ((unsigned)f2bf(xv.y) << 16) | f2bf(xv.x);

            const int o = off[node];
            const int c = cnt[node];
            int e = 0;
            for (; e + 8 <= c; e += 8) {  // 2 pipelined 4-edge groups
                const int s0 = srcbuf[o + e + g16];
                const int s1 = srcbuf[o + e + 4 + g16];
                const uint2 v0 = xf8[(size_t)s0 * 16 + q];
                const uint2 v1 = xf8[(size_t)s1 * 16 + q];
                {
                    auto p0 = __builtin_amdgcn_cvt_pk_f32_fp8(v0.x, false);
                    auto p1 = __builtin_amdgcn_cvt_pk_f32_fp8(v0.x, true);
                    auto p2 = __builtin_amdgcn_cvt_pk_f32_fp8(v0.y, false);
                    auto p3 = __builtin_amdgcn_cvt_pk_f32_fp8(v0.y, true);
                    acc[0] += p0[0]; acc[1] += p0[1]; acc[2] += p1[0]; acc[3] += p1[1];
                    acc[4] += p2[0]; acc[5] += p2[1]; acc[6] += p3[0]; acc[7] += p3[1];
                }
                {
                    auto p0 = __builtin_amdgcn_cvt_pk_f32_fp8(v1.x, false);
                    auto p1 = __builtin_amdgcn_cvt_pk_f32_fp8(v1.x, true);
                    auto p2 = __builtin_amdgcn_cvt_pk_f32_fp8(v1.y, false);
                    auto p3 = __builtin_amdgcn_cvt_pk_f32_fp8(v1.y, true);
                    acc[0] += p0[0]; acc[1] += p0[1]; acc[2] += p1[0]; acc[3] += p1[1];
                    acc[4] += p2[0]; acc[5] += p2[1]; acc[6] += p3[0]; acc[7] += p3[1];
                }
            }
            for (; e + 4 <= c; e += 4) {
                const int s = srcbuf[o + e + g16];
                const uint2 v = xf8[(size_t)s * 16 + q];
                auto p0 = __builtin_amdgcn_cvt_pk_f32_fp8(v.x, false);
                auto p1 = __builtin_amdgcn_cvt_pk_f32_fp8(v.x, true);
                auto p2 = __builtin_amdgcn_cvt_pk_f32_fp8(v.y, false);
                auto p3 = __builtin_amdgcn_cvt_pk_f32_fp8(v.y, true);
                acc[0] += p0[0]; acc[1] += p0[1]; acc[2] += p1[0]; acc[3] += p1[1];
                acc[4] += p2[0]; acc[5] += p2[1]; acc[6] += p3[0]; acc[7] += p3[1];
            }
            const int rem = c - e;
            if (g16 < rem) {
                const int s = srcbuf[o + e + g16];
                const uint2 v = xf8[(size_t)s * 16 + q];
                auto p0 = __builtin_amdgcn_cvt_pk_f32_fp8(v.x, false);
                auto p1 = __builtin_amdgcn_cvt_pk_f32_fp8(v.x, true);
                auto p2 = __builtin_amdgcn_cvt_pk_f32_fp8(v.y, false);
                auto p3 = __builtin_amdgcn_cvt_pk_f32_fp8(v.y, true);
                acc[0] += p0[0]; acc[1] += p0[1]; acc[2] += p1[0]; acc[3] += p1[1];
                acc[4] += p2[0]; acc[5] += p2[1]; acc[6] += p3[0]; acc[7] += p3[1];
            }
            // reduce across the 4 edge-slot groups (all lanes end with totals)
#pragma unroll
            for (int j = 0; j < 8; ++j) {
                acc[j] += __shfl_xor(acc[j], 16);
                acc[j] += __shfl_xor(acc[j], 32);
            }
            const float r = 1.0f / fmaxf((float)c, 1.0f);
#pragma unroll
            for (int j = 0; j < 8; ++j) acc[j] *= r;
        }

        const int sw = (((lane >> 2) ^ (ln & 15)) << 2) | (lane & 3);
        x_u[ln * 64 + sw] = xw;
        if (lane < 16) {
            uint4 mp;
            mp.x = ((unsigned)f2bf(acc[1]) << 16) | f2bf(acc[0]);
            mp.y = ((unsigned)f2bf(acc[3]) << 16) | f2bf(acc[2]);
            mp.z = ((unsigned)f2bf(acc[5]) << 16) | f2bf(acc[4]);
            mp.w = ((unsigned)f2bf(acc[7]) << 16) | f2bf(acc[6]);
            mean4[ln * 16 + (q ^ (ln & 15))] = mp;
        }
    }
    __syncthreads();

    // ---- MFMA phase ----
    const int m = w & 1;
    const int nq = w >> 1;
    const int row16 = lane & 15;
    const int kgrp = lane >> 4;
    const int ln2 = m * 16 + row16;

    bf16x8 am[4], ax[4];
#pragma unroll
    for (int kk = 0; kk < 4; ++kk) {
        const int unit = (kk * 4 + kgrp) ^ row16;
        B8 va, vb;
        va.u = mean4[ln2 * 16 + unit];
        vb.u = xls4[ln2 * 16 + unit];
        am[kk] = va.s;
        ax[kk] = vb.s;
    }

    f32x4 acc[4];
#pragma unroll
    for (int j = 0; j < 4; ++j) {
        const float bv = bl[(nq * 4 + j) * 16 + row16];
        acc[j] = (f32x4){bv, bv, bv, bv};
    }

#pragma unroll
    for (int j = 0; j < 4; ++j) {
        const int nt = nq * 4 + j;
        const uint4* pl = wpack + (size_t)(nt * 4) * 64 + lane;
        const uint4* pr = wpack + (size_t)((8 + nt) * 4) * 64 + lane;
        B8 wl[4], wr[4];
#pragma unroll
        for (int kk = 0; kk < 4; ++kk) {
            wl[kk].u = pl[kk * 64];
            wr[kk].u = pr[kk * 64];
        }
#pragma unroll
        for (int kk = 0; kk < 4; ++kk)
            acc[j] = __builtin_amdgcn_mfma_f32_16x16x32_bf16(am[kk], wl[kk].s, acc[j], 0, 0, 0);
#pragma unroll
        for (int kk = 0; kk < 4; ++kk)
            acc[j] = __builtin_amdgcn_mfma_f32_16x16x32_bf16(ax[kk], wr[kk].s, acc[j], 0, 0, 0);
    }

    // ---- relu + store h + BN partials ----
#pragma unroll
    for (int j = 0; j < 4; ++j) {
        const int feat = (nq * 4 + j) * 16 + row16;
        float s = 0.f, sq = 0.f;
#pragma unroll
        for (int r = 0; r < 4; ++r) {
            const int node = base + m * 16 + kgrp * 4 + r;
            const float v = fmaxf(acc[j][r], 0.0f);
            if (node < nn) {
                hout[(size_t)node * DIM + feat] = v;
                s += v;
                sq += v * v;
            }
        }
        s += __shfl_xor(s, 16);
        s += __shfl_xor(s, 32);
        sq += __shfl_xor(sq, 16);
        sq += __shfl_xor(sq, 32);
        if (lane < 16) {
            red_sum[m][feat] = s;
            red_sq[m][feat] = sq;
        }
    }
    __syncthreads();
    if (tid < DIM) {
        atomicAdd(&ssum[tid], red_sum[0][tid] + red_sum[1][tid]);
        atomicAdd(&ssq[tid], red_sq[0][tid] + red_sq[1][tid]);
    }
}

// ---------------------------------------------------------------------------
// Finalize: out = x + (h - mu) * rsqrt(var+eps) * gamma + beta (in-place on h).
// ---------------------------------------------------------------------------
__global__ void k_finalize(const float* __restrict__ x, const float* __restrict__ ssum,
                           const float* __restrict__ ssq, const float* __restrict__ gamma,
                           const float* __restrict__ beta, float* __restrict__ out,
                           int nn)
{
    const float invN = 1.0f / (float)nn;
    const int total4 = nn * DIM / 4;
    const int stride = gridDim.x * blockDim.x;
    for (int i = blockIdx.x * blockDim.x + threadIdx.x; i < total4; i += stride) {
        const int dv = i & 31;
        const float4 h4 = ((const float4*)out)[i];
        const float4 x4 = ((const float4*)x)[i];
        const float4 s4 = ((const float4*)ssum)[dv];
        const float4 q4 = ((const float4*)ssq)[dv];
        const float4 g4 = ((const float4*)gamma)[dv];
        const float4 b4 = ((const float4*)beta)[dv];
        float4 o;
        {
            const float mu = s4.x * invN;
            const float rs = rsqrtf(q4.x * invN - mu * mu + BN_EPS);
            o.x = x4.x + (h4.x - mu) * rs * g4.x + b4.x;
        }
        {
            const float mu = s4.y * invN;
            const float rs = rsqrtf(q4.y * invN - mu * mu + BN_EPS);
            o.y = x4.y + (h4.y - mu) * rs * g4.y + b4.y;
        }
        {
            const float mu = s4.z * invN;
            const float rs = rsqrtf(q4.z * invN - mu * mu + BN_EPS);
            o.z = x4.z + (h4.z - mu) * rs * g4.z + b4.z;
        }
        {
            const float mu = s4.w * invN;
            const float rs = rsqrtf(q4.w * invN - mu * mu + BN_EPS);
            o.w = x4.w + (h4.w - mu) * rs * g4.w + b4.w;
        }
        ((float4*)out)[i] = o;
    }
}

extern "C" void kernel_launch(void* const* d_in, const int* in_sizes, int n_in,
                              void* d_out, int out_size, void* d_ws, size_t ws_size,
                              hipStream_t stream) {
    const float* x     = (const float*)d_in[0];
    const void*  ei    = d_in[1];
    const float* Wl    = (const float*)d_in[2];
    const float* bl    = (const float*)d_in[3];
    const float* Wr    = (const float*)d_in[4];
    const float* gamma = (const float*)d_in[5];
    const float* beta  = (const float*)d_in[6];
    float* out = (float*)d_out;

    const int nn = in_sizes[0] / DIM;   // 100000
    const int ne = in_sizes[1] / 2;     // 1600000

    // workspace layout (~20.5 MB)
    int*   cnt    = (int*)d_ws;                      // nn
    float* ssum   = (float*)(cnt + nn);              // 128
    float* ssq    = ssum + DIM;                      // 128
    int*   off    = (int*)(ssq + DIM);               // nn
    int*   cursor = off + nn;                        // nn
    int*   bsum   = cursor + nn;                     // 128
    size_t pos = (size_t)3 * nn + 2 * DIM + 128;
    pos = (pos + 3) & ~(size_t)3;
    uint4* wpack  = (uint4*)((int*)d_ws + pos);      // 4096 uint4
    int*   srcbuf = (int*)(wpack + 4096);            // ne
    size_t p2 = (size_t)(srcbuf + ne - (int*)d_ws);
    p2 = (p2 + 3) & ~(size_t)3;
    uint2* xf8    = (uint2*)((int*)d_ws + p2);       // nn*16 uint2 (fp8 rows)

    hipMemsetAsync(d_ws, 0, (size_t)(nn + 2 * DIM) * sizeof(int), stream);

    const int PB = (nn * DIM / 8 + 255) / 256;   // 6250
    const int WB = 16;
    const int HB = (ne + 255) / 256;             // 6250
    k_prep<<<PB + WB + HB, 256, 0, stream>>>((const float4*)x, Wl, Wr,
                                             (const unsigned*)ei, cnt, xf8, wpack,
                                             nn, ne, PB, WB);
    const int nblk = (nn + SCAN_T - 1) / SCAN_T;
    k_scan1<<<nblk, SCAN_T, 0, stream>>>(cnt, off, bsum, nn);
    k_scan2<<<1, 64, 0, stream>>>(bsum, nblk);
    k_scan3<<<(nn + 255) / 256, 256, 0, stream>>>(off, bsum, cursor, nn);
    k_bin<<<HB, 256, 0, stream>>>((const unsigned*)ei, cursor, srcbuf, ne);
    k_gemm<<<(nn + NB - 1) / NB, 256, 0, stream>>>(x, xf8, wpack, bl, off, cnt, srcbuf,
                                                   out, ssum, ssq, nn);
    k_finalize<<<2048, 256, 0, stream>>>(x, ssum, ssq, gamma, beta, out, nn);
}

// Round 5
// 324.175 us; speedup vs baseline: 2.8877x; 1.1096x over previous
//
#include <hip/hip_runtime.h>

#define DIM 128
#define BN_EPS 1e-5f
#define NB 32
#define SCAN_T 1024

typedef __attribute__((ext_vector_type(8))) short bf16x8;
typedef __attribute__((ext_vector_type(4))) float f32x4;

union B8 { uint4 u; bf16x8 s; };

__device__ __forceinline__ ushort f2bf(float f) {
    unsigned u = __float_as_uint(f);
    u += 0x7fffu + ((u >> 16) & 1u);          // RNE
    return (ushort)(u >> 16);
}

// ---------------------------------------------------------------------------
// Fused prep: [0,PB) x->fp8 | [PB,PB+WB) pack W | [PB+WB, +HB) degree hist.
// Hist blocks self-detect int64 vs int32 (256 odd words all zero => int64).
// ---------------------------------------------------------------------------
__global__ void k_prep(const float4* __restrict__ x4, const float* __restrict__ Wl,
                       const float* __restrict__ Wr, const unsigned* __restrict__ eiu,
                       int* __restrict__ cnt, uint2* __restrict__ xf8,
                       uint4* __restrict__ wpack, int nn, int ne, int PB, int WB) {
    __shared__ int nz;
    int b = blockIdx.x;
    const int tid = threadIdx.x;

    if (b < PB) {                       // ---- x -> fp8 (e4m3), 8 elems/thread ----
        const int t = b * 256 + tid;
        const int n8 = nn * DIM / 8;
        if (t < n8) {
            const float4 a = x4[2 * t], c = x4[2 * t + 1];
            int u0 = __builtin_amdgcn_cvt_pk_fp8_f32(a.x, a.y, 0, false);
            u0 = __builtin_amdgcn_cvt_pk_fp8_f32(a.z, a.w, u0, true);
            int u1 = __builtin_amdgcn_cvt_pk_fp8_f32(c.x, c.y, 0, false);
            u1 = __builtin_amdgcn_cvt_pk_fp8_f32(c.z, c.w, u1, true);
            xf8[t] = make_uint2((unsigned)u0, (unsigned)u1);
        }
        return;
    }
    b -= PB;
    if (b < WB) {                       // ---- pack Wl/Wr into MFMA B-fragments ----
        const int t = b * 256 + tid;    // 0..4095
        const int lane = t & 63, kk = (t >> 6) & 3, nt = (t >> 8) & 7, mat = t >> 11;
        const float* W = mat ? Wr : Wl;
        const int k0 = kk * 32 + (lane >> 4) * 8;
        const int n = nt * 16 + (lane & 15);
        ushort e[8];
#pragma unroll
        for (int j = 0; j < 8; ++j) e[j] = f2bf(W[(size_t)(k0 + j) * DIM + n]);
        uint4 o;
        o.x = ((unsigned)e[1] << 16) | e[0];
        o.y = ((unsigned)e[3] << 16) | e[2];
        o.z = ((unsigned)e[5] << 16) | e[4];
        o.w = ((unsigned)e[7] << 16) | e[6];
        wpack[t] = o;
        return;
    }
    b -= WB;                            // ---- degree histogram, self-detect dtype ----
    if (tid == 0) nz = 0;
    __syncthreads();
    const int e = b * 256 + tid;
    const int es = (e < ne) ? e : (ne - 1);
    if (eiu[2 * (size_t)es + 1] != 0) atomicOr(&nz, 1);
    __syncthreads();
    if (e >= ne) return;
    int dst;
    if (nz == 0) dst = (int)((const long long*)eiu)[(size_t)ne + e];
    else         dst = ((const int*)eiu)[(size_t)ne + e];
    atomicAdd(&cnt[dst], 1);
}

// ---------------------------------------------------------------------------
// Exclusive prefix scan of cnt -> off (1024-chunks) + per-chunk sums.
// ---------------------------------------------------------------------------
__global__ __launch_bounds__(SCAN_T) void k_scan1(const int* __restrict__ cnt,
                                                  int* __restrict__ off,
                                                  int* __restrict__ bsum, int nn) {
    __shared__ int sd[SCAN_T];
    const int tid = threadIdx.x;
    const int i = blockIdx.x * SCAN_T + tid;
    const int v = (i < nn) ? cnt[i] : 0;
    sd[tid] = v;
    __syncthreads();
    for (int ofs = 1; ofs < SCAN_T; ofs <<= 1) {
        const int t = (tid >= ofs) ? sd[tid - ofs] : 0;
        __syncthreads();
        sd[tid] += t;
        __syncthreads();
    }
    if (i < nn) off[i] = sd[tid] - v;
    if (tid == SCAN_T - 1) bsum[blockIdx.x] = sd[tid];
}

// ---------------------------------------------------------------------------
// Fixup: add prefix of bsum (computed in-block via wave reduce) to off; also
// init cursor. Each 256-thread block lies in one 1024-chunk (b = blk>>2).
// ---------------------------------------------------------------------------
__global__ void k_scan3(int* __restrict__ off, const int* __restrict__ bsum,
                        int* __restrict__ cursor, int nn, int nblk) {
    __shared__ int pre_s;
    const int tid = threadIdx.x;
    const int b = blockIdx.x >> 2;
    if (tid < 64) {
        int v = 0;
        if (tid < b) v = bsum[tid];
        if (tid + 64 < b && tid + 64 < nblk) v += bsum[tid + 64];
#pragma unroll
        for (int ofs = 1; ofs < 64; ofs <<= 1) v += __shfl_xor(v, ofs);
        if (tid == 0) pre_s = v;
    }
    __syncthreads();
    const int i = blockIdx.x * 256 + tid;
    if (i >= nn) return;
    const int o = off[i] + pre_s;
    off[i] = o;
    cursor[i] = o;
}

// ---------------------------------------------------------------------------
// Bin edges into CSR by dst (self-detect dtype).
// ---------------------------------------------------------------------------
__global__ void k_bin(const unsigned* __restrict__ eiu, int* __restrict__ cursor,
                      int* __restrict__ srcbuf, int ne) {
    __shared__ int nz;
    if (threadIdx.x == 0) nz = 0;
    __syncthreads();
    const int e = blockIdx.x * blockDim.x + threadIdx.x;
    const int es = (e < ne) ? e : (ne - 1);
    if (eiu[2 * (size_t)es + 1] != 0) atomicOr(&nz, 1);
    __syncthreads();
    if (e >= ne) return;
    int src, dst;
    if (nz == 0) {
        const long long* p = (const long long*)eiu;
        src = (int)p[e];
        dst = (int)p[(size_t)ne + e];
    } else {
        const int* p = (const int*)eiu;
        src = p[e];
        dst = p[(size_t)ne + e];
    }
    const int pos = atomicAdd(&cursor[dst], 1);
    srcbuf[pos] = src;
}

// ---------------------------------------------------------------------------
// Fused: fp8 gather-mean + dual bf16 MFMA GEMM + bias + relu + BN partials.
// 512 threads = 8 waves; NB=32 nodes. Each wave gathers 4 nodes (fewer serial
// rounds, 2x resident waves for latency hiding). MFMA: wave w -> m=(w&1),
// n-tiles {(w>>1)*2, +1}. h stored bf16 to workspace.
// ---------------------------------------------------------------------------
__global__ __launch_bounds__(512, 4) void k_gemm(
    const float* __restrict__ x, const uint2* __restrict__ xf8,
    const uint4* __restrict__ wpack, const float* __restrict__ bl,
    const int* __restrict__ off, const int* __restrict__ cnt,
    const int* __restrict__ srcbuf,
    ushort* __restrict__ hout, float* __restrict__ ssum, float* __restrict__ ssq,
    int nn)
{
    __shared__ uint4 mean4[NB * 16];
    __shared__ uint4 xls4[NB * 16];
    __shared__ float red_sum[2][DIM];
    __shared__ float red_sq[2][DIM];
    unsigned* x_u = (unsigned*)xls4;

    const int tid = threadIdx.x;
    const int lane = tid & 63;
    const int w = tid >> 6;
    const int base = blockIdx.x * NB;
    const int g16 = lane >> 4;
    const int q = lane & 15;

    // ---- gather-mean phase: wave w fills rows [w*4, w*4+4) ----
    for (int n = 0; n < 4; ++n) {
        const int ln = w * 4 + n;
        const int node = base + ln;
        float acc[8];
#pragma unroll
        for (int j = 0; j < 8; ++j) acc[j] = 0.f;
        unsigned xw = 0;

        if (node < nn) {                 // wave-uniform branch
            const float2 xv = *(const float2*)(x + (size_t)node * DIM + 2 * lane);
            xw = ((unsigned)f2bf(xv.y) << 16) | f2bf(xv.x);

            const int o = off[node];
            const int c = cnt[node];
            int e = 0;
            for (; e + 8 <= c; e += 8) {  // 2 pipelined 4-edge groups
                const int s0 = srcbuf[o + e + g16];
                const int s1 = srcbuf[o + e + 4 + g16];
                const uint2 v0 = xf8[(size_t)s0 * 16 + q];
                const uint2 v1 = xf8[(size_t)s1 * 16 + q];
                {
                    auto p0 = __builtin_amdgcn_cvt_pk_f32_fp8(v0.x, false);
                    auto p1 = __builtin_amdgcn_cvt_pk_f32_fp8(v0.x, true);
                    auto p2 = __builtin_amdgcn_cvt_pk_f32_fp8(v0.y, false);
                    auto p3 = __builtin_amdgcn_cvt_pk_f32_fp8(v0.y, true);
                    acc[0] += p0[0]; acc[1] += p0[1]; acc[2] += p1[0]; acc[3] += p1[1];
                    acc[4] += p2[0]; acc[5] += p2[1]; acc[6] += p3[0]; acc[7] += p3[1];
                }
                {
                    auto p0 = __builtin_amdgcn_cvt_pk_f32_fp8(v1.x, false);
                    auto p1 = __builtin_amdgcn_cvt_pk_f32_fp8(v1.x, true);
                    auto p2 = __builtin_amdgcn_cvt_pk_f32_fp8(v1.y, false);
                    auto p3 = __builtin_amdgcn_cvt_pk_f32_fp8(v1.y, true);
                    acc[0] += p0[0]; acc[1] += p0[1]; acc[2] += p1[0]; acc[3] += p1[1];
                    acc[4] += p2[0]; acc[5] += p2[1]; acc[6] += p3[0]; acc[7] += p3[1];
                }
            }
            for (; e + 4 <= c; e += 4) {
                const int s = srcbuf[o + e + g16];
                const uint2 v = xf8[(size_t)s * 16 + q];
                auto p0 = __builtin_amdgcn_cvt_pk_f32_fp8(v.x, false);
                auto p1 = __builtin_amdgcn_cvt_pk_f32_fp8(v.x, true);
                auto p2 = __builtin_amdgcn_cvt_pk_f32_fp8(v.y, false);
                auto p3 = __builtin_amdgcn_cvt_pk_f32_fp8(v.y, true);
                acc[0] += p0[0]; acc[1] += p0[1]; acc[2] += p1[0]; acc[3] += p1[1];
                acc[4] += p2[0]; acc[5] += p2[1]; acc[6] += p3[0]; acc[7] += p3[1];
            }
            const int rem = c - e;
            if (g16 < rem) {
                const int s = srcbuf[o + e + g16];
                const uint2 v = xf8[(size_t)s * 16 + q];
                auto p0 = __builtin_amdgcn_cvt_pk_f32_fp8(v.x, false);
                auto p1 = __builtin_amdgcn_cvt_pk_f32_fp8(v.x, true);
                auto p2 = __builtin_amdgcn_cvt_pk_f32_fp8(v.y, false);
                auto p3 = __builtin_amdgcn_cvt_pk_f32_fp8(v.y, true);
                acc[0] += p0[0]; acc[1] += p0[1]; acc[2] += p1[0]; acc[3] += p1[1];
                acc[4] += p2[0]; acc[5] += p2[1]; acc[6] += p3[0]; acc[7] += p3[1];
            }
#pragma unroll
            for (int j = 0; j < 8; ++j) {
                acc[j] += __shfl_xor(acc[j], 16);
                acc[j] += __shfl_xor(acc[j], 32);
            }
            const float r = 1.0f / fmaxf((float)c, 1.0f);
#pragma unroll
            for (int j = 0; j < 8; ++j) acc[j] *= r;
        }

        const int sw = (((lane >> 2) ^ (ln & 15)) << 2) | (lane & 3);
        x_u[ln * 64 + sw] = xw;
        if (lane < 16) {
            uint4 mp;
            mp.x = ((unsigned)f2bf(acc[1]) << 16) | f2bf(acc[0]);
            mp.y = ((unsigned)f2bf(acc[3]) << 16) | f2bf(acc[2]);
            mp.z = ((unsigned)f2bf(acc[5]) << 16) | f2bf(acc[4]);
            mp.w = ((unsigned)f2bf(acc[7]) << 16) | f2bf(acc[6]);
            mean4[ln * 16 + (q ^ (ln & 15))] = mp;
        }
    }
    __syncthreads();

    // ---- MFMA phase: wave w -> m = w&1, n-tiles nh*2 + {0,1} ----
    const int m = w & 1;
    const int nh = w >> 1;
    const int row16 = lane & 15;
    const int kgrp = lane >> 4;
    const int ln2 = m * 16 + row16;

    bf16x8 am[4], ax[4];
#pragma unroll
    for (int kk = 0; kk < 4; ++kk) {
        const int unit = (kk * 4 + kgrp) ^ row16;
        B8 va, vb;
        va.u = mean4[ln2 * 16 + unit];
        vb.u = xls4[ln2 * 16 + unit];
        am[kk] = va.s;
        ax[kk] = vb.s;
    }

    f32x4 acc[2];
#pragma unroll
    for (int j = 0; j < 2; ++j) {
        const float bv = bl[(nh * 2 + j) * 16 + row16];
        acc[j] = (f32x4){bv, bv, bv, bv};
    }

#pragma unroll
    for (int j = 0; j < 2; ++j) {
        const int nt = nh * 2 + j;
        const uint4* pl = wpack + (size_t)(nt * 4) * 64 + lane;
        const uint4* pr = wpack + (size_t)((8 + nt) * 4) * 64 + lane;
        B8 wl[4], wr[4];
#pragma unroll
        for (int kk = 0; kk < 4; ++kk) {
            wl[kk].u = pl[kk * 64];
            wr[kk].u = pr[kk * 64];
        }
#pragma unroll
        for (int kk = 0; kk < 4; ++kk)
            acc[j] = __builtin_amdgcn_mfma_f32_16x16x32_bf16(am[kk], wl[kk].s, acc[j], 0, 0, 0);
#pragma unroll
        for (int kk = 0; kk < 4; ++kk)
            acc[j] = __builtin_amdgcn_mfma_f32_16x16x32_bf16(ax[kk], wr[kk].s, acc[j], 0, 0, 0);
    }

    // ---- relu + store h (bf16) + BN partials ----
#pragma unroll
    for (int j = 0; j < 2; ++j) {
        const int feat = (nh * 2 + j) * 16 + row16;
        float s = 0.f, sq = 0.f;
#pragma unroll
        for (int r = 0; r < 4; ++r) {
            const int node = base + m * 16 + kgrp * 4 + r;
            const float v = fmaxf(acc[j][r], 0.0f);
            if (node < nn) {
                hout[(size_t)node * DIM + feat] = f2bf(v);
                s += v;
                sq += v * v;
            }
        }
        s += __shfl_xor(s, 16);
        s += __shfl_xor(s, 32);
        sq += __shfl_xor(sq, 16);
        sq += __shfl_xor(sq, 32);
        if (lane < 16) {
            red_sum[m][feat] = s;
            red_sq[m][feat] = sq;
        }
    }
    __syncthreads();
    if (tid < DIM) {
        atomicAdd(&ssum[tid], red_sum[0][tid] + red_sum[1][tid]);
        atomicAdd(&ssq[tid], red_sq[0][tid] + red_sq[1][tid]);
    }
}

// ---------------------------------------------------------------------------
// Finalize: out = x + (h - mu) * rsqrt(var+eps) * gamma + beta; h is bf16.
// 8 elems/thread.
// ---------------------------------------------------------------------------
__global__ void k_finalize(const float* __restrict__ x, const uint4* __restrict__ h8,
                           const float* __restrict__ ssum, const float* __restrict__ ssq,
                           const float* __restrict__ gamma, const float* __restrict__ beta,
                           float* __restrict__ out, int nn)
{
    const float invN = 1.0f / (float)nn;
    const int total8 = nn * DIM / 8;
    const int stride = gridDim.x * blockDim.x;
    for (int i = blockIdx.x * blockDim.x + threadIdx.x; i < total8; i += stride) {
        const int f4 = 2 * (i & 15);           // float4-group index of feature octet
        const uint4 hv = h8[i];
        const float4 xa = ((const float4*)x)[2 * i];
        const float4 xb = ((const float4*)x)[2 * i + 1];
        const float4 s4a = ((const float4*)ssum)[f4], s4b = ((const float4*)ssum)[f4 + 1];
        const float4 q4a = ((const float4*)ssq)[f4], q4b = ((const float4*)ssq)[f4 + 1];
        const float4 g4a = ((const float4*)gamma)[f4], g4b = ((const float4*)gamma)[f4 + 1];
        const float4 b4a = ((const float4*)beta)[f4], b4b = ((const float4*)beta)[f4 + 1];
        float h[8];
        h[0] = __uint_as_float(hv.x << 16);
        h[1] = __uint_as_float(hv.x & 0xffff0000u);
        h[2] = __uint_as_float(hv.y << 16);
        h[3] = __uint_as_float(hv.y & 0xffff0000u);
        h[4] = __uint_as_float(hv.z << 16);
        h[5] = __uint_as_float(hv.z & 0xffff0000u);
        h[6] = __uint_as_float(hv.w << 16);
        h[7] = __uint_as_float(hv.w & 0xffff0000u);
        float4 oa, ob;
        {
            const float mu = s4a.x * invN, rs = rsqrtf(q4a.x * invN - mu * mu + BN_EPS);
            oa.x = xa.x + (h[0] - mu) * rs * g4a.x + b4a.x;
        }
        {
            const float mu = s4a.y * invN, rs = rsqrtf(q4a.y * invN - mu * mu + BN_EPS);
            oa.y = xa.y + (h[1] - mu) * rs * g4a.y + b4a.y;
        }
        {
            const float mu = s4a.z * invN, rs = rsqrtf(q4a.z * invN - mu * mu + BN_EPS);
            oa.z = xa.z + (h[2] - mu) * rs * g4a.z + b4a.z;
        }
        {
            const float mu = s4a.w * invN, rs = rsqrtf(q4a.w * invN - mu * mu + BN_EPS);
            oa.w = xa.w + (h[3] - mu) * rs * g4a.w + b4a.w;
        }
        {
            const float mu = s4b.x * invN, rs = rsqrtf(q4b.x * invN - mu * mu + BN_EPS);
            ob.x = xb.x + (h[4] - mu) * rs * g4b.x + b4b.x;
        }
        {
            const float mu = s4b.y * invN, rs = rsqrtf(q4b.y * invN - mu * mu + BN_EPS);
            ob.y = xb.y + (h[5] - mu) * rs * g4b.y + b4b.y;
        }
        {
            const float mu = s4b.z * invN, rs = rsqrtf(q4b.z * invN - mu * mu + BN_EPS);
            ob.z = xb.z + (h[6] - mu) * rs * g4b.z + b4b.z;
        }
        {
            const float mu = s4b.w * invN, rs = rsqrtf(q4b.w * invN - mu * mu + BN_EPS);
            ob.w = xb.w + (h[7] - mu) * rs * g4b.w + b4b.w;
        }
        ((float4*)out)[2 * i] = oa;
        ((float4*)out)[2 * i + 1] = ob;
    }
}

extern "C" void kernel_launch(void* const* d_in, const int* in_sizes, int n_in,
                              void* d_out, int out_size, void* d_ws, size_t ws_size,
                              hipStream_t stream) {
    const float* x     = (const float*)d_in[0];
    const void*  ei    = d_in[1];
    const float* Wl    = (const float*)d_in[2];
    const float* bl    = (const float*)d_in[3];
    const float* Wr    = (const float*)d_in[4];
    const float* gamma = (const float*)d_in[5];
    const float* beta  = (const float*)d_in[6];
    float* out = (float*)d_out;

    const int nn = in_sizes[0] / DIM;   // 100000
    const int ne = in_sizes[1] / 2;     // 1600000

    // workspace layout (~46 MB)
    int*   cnt    = (int*)d_ws;                      // nn
    float* ssum   = (float*)(cnt + nn);              // 128
    float* ssq    = ssum + DIM;                      // 128
    int*   off    = (int*)(ssq + DIM);               // nn
    int*   cursor = off + nn;                        // nn
    int*   bsum   = cursor + nn;                     // 128
    size_t pos = (size_t)3 * nn + 2 * DIM + 128;
    pos = (pos + 3) & ~(size_t)3;
    uint4* wpack  = (uint4*)((int*)d_ws + pos);      // 4096 uint4
    int*   srcbuf = (int*)(wpack + 4096);            // ne
    size_t p2 = (size_t)(srcbuf + ne - (int*)d_ws);
    p2 = (p2 + 3) & ~(size_t)3;
    uint2* xf8    = (uint2*)((int*)d_ws + p2);       // nn*16 uint2 (fp8 rows)
    ushort* hbuf  = (ushort*)(xf8 + (size_t)nn * 16); // nn*128 bf16

    hipMemsetAsync(d_ws, 0, (size_t)(nn + 2 * DIM) * sizeof(int), stream);

    const int PB = (nn * DIM / 8 + 255) / 256;   // 6250
    const int WB = 16;
    const int HB = (ne + 255) / 256;             // 6250
    k_prep<<<PB + WB + HB, 256, 0, stream>>>((const float4*)x, Wl, Wr,
                                             (const unsigned*)ei, cnt, xf8, wpack,
                                             nn, ne, PB, WB);
    const int nblk = (nn + SCAN_T - 1) / SCAN_T;
    k_scan1<<<nblk, SCAN_T, 0, stream>>>(cnt, off, bsum, nn);
    k_scan3<<<(nn + 255) / 256, 256, 0, stream>>>(off, bsum, cursor, nn, nblk);
    k_bin<<<HB, 256, 0, stream>>>((const unsigned*)ei, cursor, srcbuf, ne);
    k_gemm<<<(nn + NB - 1) / NB, 512, 0, stream>>>(x, xf8, wpack, bl, off, cnt, srcbuf,
                                                   hbuf, ssum, ssq, nn);
    k_finalize<<<2048, 256, 0, stream>>>(x, (const uint4*)hbuf, ssum, ssq, gamma, beta,
                                         out, nn);
}

// Round 6
// 194.153 us; speedup vs baseline: 4.8216x; 1.6697x over previous
//
#include <hip/hip_runtime.h>

#define DIM 128
#define BN_EPS 1e-5f
#define NB 32
#define NBK_MAX 512

typedef __attribute__((ext_vector_type(8))) short bf16x8;
typedef __attribute__((ext_vector_type(4))) float f32x4;

union B8 { uint4 u; bf16x8 s; };

__device__ __forceinline__ ushort f2bf(float f) {
    unsigned u = __float_as_uint(f);
    u += 0x7fffu + ((u >> 16) & 1u);          // RNE
    return (ushort)(u >> 16);
}

// ---------------------------------------------------------------------------
// Fused prep: [0,PB) x->fp8 | [PB,PB+WB) pack W | [PB+WB,+HB) bucket hist.
// Bucket = dst>>8 (256 nodes/bucket). Blocks self-detect int64 vs int32
// (256 sampled odd words all zero => int64).
// ---------------------------------------------------------------------------
__global__ void k_prep(const float4* __restrict__ x4, const float* __restrict__ Wl,
                       const float* __restrict__ Wr, const unsigned* __restrict__ eiu,
                       int* __restrict__ bcnt, uint2* __restrict__ xf8,
                       uint4* __restrict__ wpack, int nn, int ne, int PB, int WB) {
    __shared__ int nz;
    __shared__ int lh[NBK_MAX];
    int b = blockIdx.x;
    const int tid = threadIdx.x;

    if (b < PB) {                       // ---- x -> fp8 (e4m3), 8 elems/thread ----
        const int t = b * 256 + tid;
        const int n8 = nn * DIM / 8;
        if (t < n8) {
            const float4 a = x4[2 * t], c = x4[2 * t + 1];
            int u0 = __builtin_amdgcn_cvt_pk_fp8_f32(a.x, a.y, 0, false);
            u0 = __builtin_amdgcn_cvt_pk_fp8_f32(a.z, a.w, u0, true);
            int u1 = __builtin_amdgcn_cvt_pk_fp8_f32(c.x, c.y, 0, false);
            u1 = __builtin_amdgcn_cvt_pk_fp8_f32(c.z, c.w, u1, true);
            xf8[t] = make_uint2((unsigned)u0, (unsigned)u1);
        }
        return;
    }
    b -= PB;
    if (b < WB) {                       // ---- pack Wl/Wr into MFMA B-fragments ----
        const int t = b * 256 + tid;    // 0..4095
        const int lane = t & 63, kk = (t >> 6) & 3, nt = (t >> 8) & 7, mat = t >> 11;
        const float* W = mat ? Wr : Wl;
        const int k0 = kk * 32 + (lane >> 4) * 8;
        const int n = nt * 16 + (lane & 15);
        ushort e[8];
#pragma unroll
        for (int j = 0; j < 8; ++j) e[j] = f2bf(W[(size_t)(k0 + j) * DIM + n]);
        uint4 o;
        o.x = ((unsigned)e[1] << 16) | e[0];
        o.y = ((unsigned)e[3] << 16) | e[2];
        o.z = ((unsigned)e[5] << 16) | e[4];
        o.w = ((unsigned)e[7] << 16) | e[6];
        wpack[t] = o;
        return;
    }
    b -= WB;                            // ---- bucket histogram (4096 edges/block) ----
    const int nbk = (nn + 255) >> 8;
    for (int i = tid; i < nbk; i += 256) lh[i] = 0;
    if (tid == 0) nz = 0;
    __syncthreads();
    const int e0 = b * 4096;
    {
        int es = e0 + tid * 16;
        if (es >= ne) es = ne - 1;
        if (eiu[2 * (size_t)es + 1] != 0) atomicOr(&nz, 1);
    }
    __syncthreads();
    const int is64 = (nz == 0);
    for (int j = 0; j < 16; ++j) {
        const int e = e0 + j * 256 + tid;
        if (e < ne) {
            int dst;
            if (is64) dst = (int)((const long long*)eiu)[(size_t)ne + e];
            else      dst = ((const int*)eiu)[(size_t)ne + e];
            atomicAdd(&lh[dst >> 8], 1);
        }
    }
    __syncthreads();
    for (int i = tid; i < nbk; i += 256)
        if (lh[i]) atomicAdd(&bcnt[i], lh[i]);
}

// ---------------------------------------------------------------------------
// Exclusive scan of bucket counts (one block, width 512 >= nbk).
// ---------------------------------------------------------------------------
__global__ __launch_bounds__(512) void k_scanb(const int* __restrict__ bcnt,
                                               int* __restrict__ bbase,
                                               int* __restrict__ cursor2, int nn, int ne) {
    __shared__ int sd[512];
    const int nbk = (nn + 255) >> 8;
    const int tid = threadIdx.x;
    const int v = (tid < nbk) ? bcnt[tid] : 0;
    sd[tid] = v;
    __syncthreads();
    for (int ofs = 1; ofs < 512; ofs <<= 1) {
        const int t = (tid >= ofs) ? sd[tid - ofs] : 0;
        __syncthreads();
        sd[tid] += t;
        __syncthreads();
    }
    if (tid < nbk) {
        const int ex = sd[tid] - v;
        bbase[tid] = ex;
        cursor2[tid] = ex;
    }
    if (tid == 0) bbase[nbk] = ne;
}

// ---------------------------------------------------------------------------
// Pass A: partition edges into buckets. Per block: LDS rank per edge, one
// global atomic per (block,bucket), write packed (local<<24|src) u32 grouped
// by bucket (~42B runs instead of 4B scatter).
// ---------------------------------------------------------------------------
__global__ __launch_bounds__(256) void k_passA(const unsigned* __restrict__ eiu,
                                               int* __restrict__ cursor2,
                                               unsigned* __restrict__ pairbuf,
                                               int nn, int ne) {
    __shared__ int lh[NBK_MAX];
    __shared__ int gb[NBK_MAX];
    __shared__ int nz;
    const int nbk = (nn + 255) >> 8;
    const int tid = threadIdx.x;
    const int e0 = blockIdx.x * 4096;
    for (int i = tid; i < nbk; i += 256) lh[i] = 0;
    if (tid == 0) nz = 0;
    __syncthreads();
    {
        int es = e0 + tid * 16;
        if (es >= ne) es = ne - 1;
        if (eiu[2 * (size_t)es + 1] != 0) atomicOr(&nz, 1);
    }
    __syncthreads();
    const int is64 = (nz == 0);
    unsigned pay[16];
    int bkrank[16];
#pragma unroll
    for (int j = 0; j < 16; ++j) {
        const int e = e0 + j * 256 + tid;
        bkrank[j] = -1;
        if (e < ne) {
            int src, dst;
            if (is64) {
                const long long* p = (const long long*)eiu;
                src = (int)p[e];
                dst = (int)p[(size_t)ne + e];
            } else {
                const int* p = (const int*)eiu;
                src = p[e];
                dst = p[(size_t)ne + e];
            }
            const int bk = dst >> 8;
            const int rank = atomicAdd(&lh[bk], 1);
            bkrank[j] = (bk << 16) | rank;
            pay[j] = ((unsigned)(dst & 255) << 24) | (unsigned)src;
        }
    }
    __syncthreads();
    for (int i = tid; i < nbk; i += 256) {
        const int c = lh[i];
        gb[i] = c ? atomicAdd(&cursor2[i], c) : 0;
    }
    __syncthreads();
#pragma unroll
    for (int j = 0; j < 16; ++j) {
        if (bkrank[j] >= 0) {
            const int bk = bkrank[j] >> 16, rank = bkrank[j] & 0xFFFF;
            pairbuf[gb[bk] + rank] = pay[j];
        }
    }
}

// ---------------------------------------------------------------------------
// Pass B: per bucket (256 nodes): per-node LDS hist + block scan -> off/cnt,
// then place srcs into the bucket's contiguous CSR window (~16 KB, L2-local).
// ---------------------------------------------------------------------------
__global__ __launch_bounds__(256) void k_passB(const unsigned* __restrict__ pairbuf,
                                               const int* __restrict__ bbase,
                                               int* __restrict__ off, int* __restrict__ cnt,
                                               int* __restrict__ srcbuf, int nn) {
    __shared__ int cl[256];
    __shared__ int sd[256];
    __shared__ int cur[256];
    const int tid = threadIdx.x;
    const int b = blockIdx.x;
    const int node0 = b << 8;
    const int e0 = bbase[b], e1 = bbase[b + 1];
    cl[tid] = 0;
    __syncthreads();
    for (int e = e0 + tid; e < e1; e += 256)
        atomicAdd(&cl[pairbuf[e] >> 24], 1);
    __syncthreads();
    const int v = cl[tid];
    sd[tid] = v;
    __syncthreads();
    for (int ofs = 1; ofs < 256; ofs <<= 1) {
        const int t = (tid >= ofs) ? sd[tid - ofs] : 0;
        __syncthreads();
        sd[tid] += t;
        __syncthreads();
    }
    const int ex = sd[tid] - v;
    cur[tid] = ex;
    const int node = node0 + tid;
    if (node < nn) {
        off[node] = e0 + ex;
        cnt[node] = v;
    }
    __syncthreads();
    for (int e = e0 + tid; e < e1; e += 256) {
        const unsigned p = pairbuf[e];
        const int pos = atomicAdd(&cur[p >> 24], 1);
        srcbuf[e0 + pos] = (int)(p & 0xFFFFFFu);
    }
}

// ---------------------------------------------------------------------------
// Fused: fp8 gather-mean + dual bf16 MFMA GEMM + bias + relu + BN partials.
// 512 threads = 8 waves; NB=32 nodes; wave gathers 4 nodes. h stored bf16.
// ---------------------------------------------------------------------------
__global__ __launch_bounds__(512, 4) void k_gemm(
    const float* __restrict__ x, const uint2* __restrict__ xf8,
    const uint4* __restrict__ wpack, const float* __restrict__ bl,
    const int* __restrict__ off, const int* __restrict__ cnt,
    const int* __restrict__ srcbuf,
    ushort* __restrict__ hout, float* __restrict__ ssum, float* __restrict__ ssq,
    int nn)
{
    __shared__ uint4 mean4[NB * 16];
    __shared__ uint4 xls4[NB * 16];
    __shared__ float red_sum[2][DIM];
    __shared__ float red_sq[2][DIM];
    unsigned* x_u = (unsigned*)xls4;

    const int tid = threadIdx.x;
    const int lane = tid & 63;
    const int w = tid >> 6;
    const int base = blockIdx.x * NB;
    const int g16 = lane >> 4;
    const int q = lane & 15;

    // ---- gather-mean phase: wave w fills rows [w*4, w*4+4) ----
    for (int n = 0; n < 4; ++n) {
        const int ln = w * 4 + n;
        const int node = base + ln;
        float acc[8];
#pragma unroll
        for (int j = 0; j < 8; ++j) acc[j] = 0.f;
        unsigned xw = 0;

        if (node < nn) {                 // wave-uniform branch
            const float2 xv = *(const float2*)(x + (size_t)node * DIM + 2 * lane);
            xw = ((unsigned)f2bf(xv.y) << 16) | f2bf(xv.x);

            const int o = off[node];
            const int c = cnt[node];
            int e = 0;
            for (; e + 8 <= c; e += 8) {  // 2 pipelined 4-edge groups
                const int s0 = srcbuf[o + e + g16];
                const int s1 = srcbuf[o + e + 4 + g16];
                const uint2 v0 = xf8[(size_t)s0 * 16 + q];
                const uint2 v1 = xf8[(size_t)s1 * 16 + q];
                {
                    auto p0 = __builtin_amdgcn_cvt_pk_f32_fp8(v0.x, false);
                    auto p1 = __builtin_amdgcn_cvt_pk_f32_fp8(v0.x, true);
                    auto p2 = __builtin_amdgcn_cvt_pk_f32_fp8(v0.y, false);
                    auto p3 = __builtin_amdgcn_cvt_pk_f32_fp8(v0.y, true);
                    acc[0] += p0[0]; acc[1] += p0[1]; acc[2] += p1[0]; acc[3] += p1[1];
                    acc[4] += p2[0]; acc[5] += p2[1]; acc[6] += p3[0]; acc[7] += p3[1];
                }
                {
                    auto p0 = __builtin_amdgcn_cvt_pk_f32_fp8(v1.x, false);
                    auto p1 = __builtin_amdgcn_cvt_pk_f32_fp8(v1.x, true);
                    auto p2 = __builtin_amdgcn_cvt_pk_f32_fp8(v1.y, false);
                    auto p3 = __builtin_amdgcn_cvt_pk_f32_fp8(v1.y, true);
                    acc[0] += p0[0]; acc[1] += p0[1]; acc[2] += p1[0]; acc[3] += p1[1];
                    acc[4] += p2[0]; acc[5] += p2[1]; acc[6] += p3[0]; acc[7] += p3[1];
                }
            }
            for (; e + 4 <= c; e += 4) {
                const int s = srcbuf[o + e + g16];
                const uint2 v = xf8[(size_t)s * 16 + q];
                auto p0 = __builtin_amdgcn_cvt_pk_f32_fp8(v.x, false);
                auto p1 = __builtin_amdgcn_cvt_pk_f32_fp8(v.x, true);
                auto p2 = __builtin_amdgcn_cvt_pk_f32_fp8(v.y, false);
                auto p3 = __builtin_amdgcn_cvt_pk_f32_fp8(v.y, true);
                acc[0] += p0[0]; acc[1] += p0[1]; acc[2] += p1[0]; acc[3] += p1[1];
                acc[4] += p2[0]; acc[5] += p2[1]; acc[6] += p3[0]; acc[7] += p3[1];
            }
            const int rem = c - e;
            if (g16 < rem) {
                const int s = srcbuf[o + e + g16];
                const uint2 v = xf8[(size_t)s * 16 + q];
                auto p0 = __builtin_amdgcn_cvt_pk_f32_fp8(v.x, false);
                auto p1 = __builtin_amdgcn_cvt_pk_f32_fp8(v.x, true);
                auto p2 = __builtin_amdgcn_cvt_pk_f32_fp8(v.y, false);
                auto p3 = __builtin_amdgcn_cvt_pk_f32_fp8(v.y, true);
                acc[0] += p0[0]; acc[1] += p0[1]; acc[2] += p1[0]; acc[3] += p1[1];
                acc[4] += p2[0]; acc[5] += p2[1]; acc[6] += p3[0]; acc[7] += p3[1];
            }
#pragma unroll
            for (int j = 0; j < 8; ++j) {
                acc[j] += __shfl_xor(acc[j], 16);
                acc[j] += __shfl_xor(acc[j], 32);
            }
            const float r = 1.0f / fmaxf((float)c, 1.0f);
#pragma unroll
            for (int j = 0; j < 8; ++j) acc[j] *= r;
        }

        const int sw = (((lane >> 2) ^ (ln & 15)) << 2) | (lane & 3);
        x_u[ln * 64 + sw] = xw;
        if (lane < 16) {
            uint4 mp;
            mp.x = ((unsigned)f2bf(acc[1]) << 16) | f2bf(acc[0]);
            mp.y = ((unsigned)f2bf(acc[3]) << 16) | f2bf(acc[2]);
            mp.z = ((unsigned)f2bf(acc[5]) << 16) | f2bf(acc[4]);
            mp.w = ((unsigned)f2bf(acc[7]) << 16) | f2bf(acc[6]);
            mean4[ln * 16 + (q ^ (ln & 15))] = mp;
        }
    }
    __syncthreads();

    // ---- MFMA phase: wave w -> m = w&1, n-tiles nh*2 + {0,1} ----
    const int m = w & 1;
    const int nh = w >> 1;
    const int row16 = lane & 15;
    const int kgrp = lane >> 4;
    const int ln2 = m * 16 + row16;

    bf16x8 am[4], ax[4];
#pragma unroll
    for (int kk = 0; kk < 4; ++kk) {
        const int unit = (kk * 4 + kgrp) ^ row16;
        B8 va, vb;
        va.u = mean4[ln2 * 16 + unit];
        vb.u = xls4[ln2 * 16 + unit];
        am[kk] = va.s;
        ax[kk] = vb.s;
    }

    f32x4 acc[2];
#pragma unroll
    for (int j = 0; j < 2; ++j) {
        const float bv = bl[(nh * 2 + j) * 16 + row16];
        acc[j] = (f32x4){bv, bv, bv, bv};
    }

#pragma unroll
    for (int j = 0; j < 2; ++j) {
        const int nt = nh * 2 + j;
        const uint4* pl = wpack + (size_t)(nt * 4) * 64 + lane;
        const uint4* pr = wpack + (size_t)((8 + nt) * 4) * 64 + lane;
        B8 wl[4], wr[4];
#pragma unroll
        for (int kk = 0; kk < 4; ++kk) {
            wl[kk].u = pl[kk * 64];
            wr[kk].u = pr[kk * 64];
        }
#pragma unroll
        for (int kk = 0; kk < 4; ++kk)
            acc[j] = __builtin_amdgcn_mfma_f32_16x16x32_bf16(am[kk], wl[kk].s, acc[j], 0, 0, 0);
#pragma unroll
        for (int kk = 0; kk < 4; ++kk)
            acc[j] = __builtin_amdgcn_mfma_f32_16x16x32_bf16(ax[kk], wr[kk].s, acc[j], 0, 0, 0);
    }

    // ---- relu + store h (bf16) + BN partials ----
#pragma unroll
    for (int j = 0; j < 2; ++j) {
        const int feat = (nh * 2 + j) * 16 + row16;
        float s = 0.f, sq = 0.f;
#pragma unroll
        for (int r = 0; r < 4; ++r) {
            const int node = base + m * 16 + kgrp * 4 + r;
            const float v = fmaxf(acc[j][r], 0.0f);
            if (node < nn) {
                hout[(size_t)node * DIM + feat] = f2bf(v);
                s += v;
                sq += v * v;
            }
        }
        s += __shfl_xor(s, 16);
        s += __shfl_xor(s, 32);
        sq += __shfl_xor(sq, 16);
        sq += __shfl_xor(sq, 32);
        if (lane < 16) {
            red_sum[m][feat] = s;
            red_sq[m][feat] = sq;
        }
    }
    __syncthreads();
    if (tid < DIM) {
        atomicAdd(&ssum[tid], red_sum[0][tid] + red_sum[1][tid]);
        atomicAdd(&ssq[tid], red_sq[0][tid] + red_sq[1][tid]);
    }
}

// ---------------------------------------------------------------------------
// Finalize: out = x + (h - mu) * rsqrt(var+eps) * gamma + beta; h is bf16.
// ---------------------------------------------------------------------------
__global__ void k_finalize(const float* __restrict__ x, const uint4* __restrict__ h8,
                           const float* __restrict__ ssum, const float* __restrict__ ssq,
                           const float* __restrict__ gamma, const float* __restrict__ beta,
                           float* __restrict__ out, int nn)
{
    const float invN = 1.0f / (float)nn;
    const int total8 = nn * DIM / 8;
    const int stride = gridDim.x * blockDim.x;
    for (int i = blockIdx.x * blockDim.x + threadIdx.x; i < total8; i += stride) {
        const int f4 = 2 * (i & 15);
        const uint4 hv = h8[i];
        const float4 xa = ((const float4*)x)[2 * i];
        const float4 xb = ((const float4*)x)[2 * i + 1];
        const float4 s4a = ((const float4*)ssum)[f4], s4b = ((const float4*)ssum)[f4 + 1];
        const float4 q4a = ((const float4*)ssq)[f4], q4b = ((const float4*)ssq)[f4 + 1];
        const float4 g4a = ((const float4*)gamma)[f4], g4b = ((const float4*)gamma)[f4 + 1];
        const float4 b4a = ((const float4*)beta)[f4], b4b = ((const float4*)beta)[f4 + 1];
        float h[8];
        h[0] = __uint_as_float(hv.x << 16);
        h[1] = __uint_as_float(hv.x & 0xffff0000u);
        h[2] = __uint_as_float(hv.y << 16);
        h[3] = __uint_as_float(hv.y & 0xffff0000u);
        h[4] = __uint_as_float(hv.z << 16);
        h[5] = __uint_as_float(hv.z & 0xffff0000u);
        h[6] = __uint_as_float(hv.w << 16);
        h[7] = __uint_as_float(hv.w & 0xffff0000u);
        float4 oa, ob;
        {
            const float mu = s4a.x * invN, rs = rsqrtf(q4a.x * invN - mu * mu + BN_EPS);
            oa.x = xa.x + (h[0] - mu) * rs * g4a.x + b4a.x;
        }
        {
            const float mu = s4a.y * invN, rs = rsqrtf(q4a.y * invN - mu * mu + BN_EPS);
            oa.y = xa.y + (h[1] - mu) * rs * g4a.y + b4a.y;
        }
        {
            const float mu = s4a.z * invN, rs = rsqrtf(q4a.z * invN - mu * mu + BN_EPS);
            oa.z = xa.z + (h[2] - mu) * rs * g4a.z + b4a.z;
        }
        {
            const float mu = s4a.w * invN, rs = rsqrtf(q4a.w * invN - mu * mu + BN_EPS);
            oa.w = xa.w + (h[3] - mu) * rs * g4a.w + b4a.w;
        }
        {
            const float mu = s4b.x * invN, rs = rsqrtf(q4b.x * invN - mu * mu + BN_EPS);
            ob.x = xb.x + (h[4] - mu) * rs * g4b.x + b4b.x;
        }
        {
            const float mu = s4b.y * invN, rs = rsqrtf(q4b.y * invN - mu * mu + BN_EPS);
            ob.y = xb.y + (h[5] - mu) * rs * g4b.y + b4b.y;
        }
        {
            const float mu = s4b.z * invN, rs = rsqrtf(q4b.z * invN - mu * mu + BN_EPS);
            ob.z = xb.z + (h[6] - mu) * rs * g4b.z + b4b.z;
        }
        {
            const float mu = s4b.w * invN, rs = rsqrtf(q4b.w * invN - mu * mu + BN_EPS);
            ob.w = xb.w + (h[7] - mu) * rs * g4b.w + b4b.w;
        }
        ((float4*)out)[2 * i] = oa;
        ((float4*)out)[2 * i + 1] = ob;
    }
}

extern "C" void kernel_launch(void* const* d_in, const int* in_sizes, int n_in,
                              void* d_out, int out_size, void* d_ws, size_t ws_size,
                              hipStream_t stream) {
    const float* x     = (const float*)d_in[0];
    const void*  ei    = d_in[1];
    const float* Wl    = (const float*)d_in[2];
    const float* bl    = (const float*)d_in[3];
    const float* Wr    = (const float*)d_in[4];
    const float* gamma = (const float*)d_in[5];
    const float* beta  = (const float*)d_in[6];
    float* out = (float*)d_out;

    const int nn = in_sizes[0] / DIM;   // 100000
    const int ne = in_sizes[1] / 2;     // 1600000
    const int nbk = (nn + 255) >> 8;    // 391

    // workspace layout (~46 MB)
    int* ws = (int*)d_ws;
    int*   bcnt    = ws;                 // 512
    float* ssum    = (float*)(ws + 512); // 128
    float* ssq     = (float*)(ws + 640); // 128
    int*   bbase   = ws + 768;           // 512 (nbk+1)
    int*   cursor2 = ws + 1280;          // 512
    int*   cnt     = ws + 1792;          // nn
    int*   off     = cnt + nn;           // nn
    size_t pos = 1792 + 2 * (size_t)nn;
    pos = (pos + 3) & ~(size_t)3;
    uint4* wpack  = (uint4*)(ws + pos);          // 4096 uint4
    int*   srcbuf = (int*)(wpack + 4096);        // ne
    size_t p2 = (size_t)(srcbuf + ne - ws);
    p2 = (p2 + 3) & ~(size_t)3;
    uint2* xf8 = (uint2*)(ws + p2);              // nn*16 uint2 (fp8 rows)
    // union region: pairbuf (passA/passB) then hbuf (gemm/finalize)
    unsigned* pairbuf = (unsigned*)(xf8 + (size_t)nn * 16);  // ne u32
    ushort*   hbuf    = (ushort*)pairbuf;                    // nn*128 bf16

    hipMemsetAsync(d_ws, 0, 768 * sizeof(int), stream);  // bcnt + ssum + ssq

    const int PB = (nn * DIM / 8 + 255) / 256;   // 6250
    const int WB = 16;
    const int HB = (ne + 4095) / 4096;           // 391
    k_prep<<<PB + WB + HB, 256, 0, stream>>>((const float4*)x, Wl, Wr,
                                             (const unsigned*)ei, bcnt, xf8, wpack,
                                             nn, ne, PB, WB);
    k_scanb<<<1, 512, 0, stream>>>(bcnt, bbase, cursor2, nn, ne);
    k_passA<<<(ne + 4095) / 4096, 256, 0, stream>>>((const unsigned*)ei, cursor2,
                                                    pairbuf, nn, ne);
    k_passB<<<nbk, 256, 0, stream>>>(pairbuf, bbase, off, cnt, srcbuf, nn);
    k_gemm<<<(nn + NB - 1) / NB, 512, 0, stream>>>(x, xf8, wpack, bl, off, cnt, srcbuf,
                                                   hbuf, ssum, ssq, nn);
    k_finalize<<<2048, 256, 0, stream>>>(x, (const uint4*)hbuf, ssum, ssq, gamma, beta,
                                         out, nn);
}

// Round 7
// 187.253 us; speedup vs baseline: 4.9992x; 1.0369x over previous
//
#include <hip/hip_runtime.h>

#define DIM 128
#define BN_EPS 1e-5f
#define NB 32
#define NBK_MAX 512

typedef __attribute__((ext_vector_type(8))) short bf16x8;
typedef __attribute__((ext_vector_type(4))) float f32x4;

union B8 { uint4 u; bf16x8 s; };

__device__ __forceinline__ ushort f2bf(float f) {
    unsigned u = __float_as_uint(f);
    u += 0x7fffu + ((u >> 16) & 1u);          // RNE
    return (ushort)(u >> 16);
}

// ---------------------------------------------------------------------------
// Fused prep: [0,PB) x->fp8 | [PB,PB+WB) pack W | [PB+WB,+HB) bucket hist.
// Bucket = dst>>8 (256 nodes/bucket). Blocks self-detect int64 vs int32.
// ---------------------------------------------------------------------------
__global__ void k_prep(const float4* __restrict__ x4, const float* __restrict__ Wl,
                       const float* __restrict__ Wr, const unsigned* __restrict__ eiu,
                       int* __restrict__ bcnt, uint2* __restrict__ xf8,
                       uint4* __restrict__ wpack, int nn, int ne, int PB, int WB) {
    __shared__ int nz;
    __shared__ int lh[NBK_MAX];
    int b = blockIdx.x;
    const int tid = threadIdx.x;

    if (b < PB) {                       // ---- x -> fp8 (e4m3), 8 elems/thread ----
        const int t = b * 256 + tid;
        const int n8 = nn * DIM / 8;
        if (t < n8) {
            const float4 a = x4[2 * t], c = x4[2 * t + 1];
            int u0 = __builtin_amdgcn_cvt_pk_fp8_f32(a.x, a.y, 0, false);
            u0 = __builtin_amdgcn_cvt_pk_fp8_f32(a.z, a.w, u0, true);
            int u1 = __builtin_amdgcn_cvt_pk_fp8_f32(c.x, c.y, 0, false);
            u1 = __builtin_amdgcn_cvt_pk_fp8_f32(c.z, c.w, u1, true);
            xf8[t] = make_uint2((unsigned)u0, (unsigned)u1);
        }
        return;
    }
    b -= PB;
    if (b < WB) {                       // ---- pack Wl/Wr into MFMA B-fragments ----
        const int t = b * 256 + tid;    // 0..4095
        const int lane = t & 63, kk = (t >> 6) & 3, nt = (t >> 8) & 7, mat = t >> 11;
        const float* W = mat ? Wr : Wl;
        const int k0 = kk * 32 + (lane >> 4) * 8;
        const int n = nt * 16 + (lane & 15);
        ushort e[8];
#pragma unroll
        for (int j = 0; j < 8; ++j) e[j] = f2bf(W[(size_t)(k0 + j) * DIM + n]);
        uint4 o;
        o.x = ((unsigned)e[1] << 16) | e[0];
        o.y = ((unsigned)e[3] << 16) | e[2];
        o.z = ((unsigned)e[5] << 16) | e[4];
        o.w = ((unsigned)e[7] << 16) | e[6];
        wpack[t] = o;
        return;
    }
    b -= WB;                            // ---- bucket histogram (4096 edges/block) ----
    const int nbk = (nn + 255) >> 8;
    for (int i = tid; i < nbk; i += 256) lh[i] = 0;
    if (tid == 0) nz = 0;
    __syncthreads();
    const int e0 = b * 4096;
    {
        int es = e0 + tid * 16;
        if (es >= ne) es = ne - 1;
        if (eiu[2 * (size_t)es + 1] != 0) atomicOr(&nz, 1);
    }
    __syncthreads();
    const int is64 = (nz == 0);
    for (int j = 0; j < 16; ++j) {
        const int e = e0 + j * 256 + tid;
        if (e < ne) {
            int dst;
            if (is64) dst = (int)((const long long*)eiu)[(size_t)ne + e];
            else      dst = ((const int*)eiu)[(size_t)ne + e];
            atomicAdd(&lh[dst >> 8], 1);
        }
    }
    __syncthreads();
    for (int i = tid; i < nbk; i += 256)
        if (lh[i]) atomicAdd(&bcnt[i], lh[i]);
}

// ---------------------------------------------------------------------------
// Exclusive scan of bucket counts (one block, width 512 >= nbk).
// ---------------------------------------------------------------------------
__global__ __launch_bounds__(512) void k_scanb(const int* __restrict__ bcnt,
                                               int* __restrict__ bbase,
                                               int* __restrict__ cursor2, int nn, int ne) {
    __shared__ int sd[512];
    const int nbk = (nn + 255) >> 8;
    const int tid = threadIdx.x;
    const int v = (tid < nbk) ? bcnt[tid] : 0;
    sd[tid] = v;
    __syncthreads();
    for (int ofs = 1; ofs < 512; ofs <<= 1) {
        const int t = (tid >= ofs) ? sd[tid - ofs] : 0;
        __syncthreads();
        sd[tid] += t;
        __syncthreads();
    }
    if (tid < nbk) {
        const int ex = sd[tid] - v;
        bbase[tid] = ex;
        cursor2[tid] = ex;
    }
    if (tid == 0) bbase[nbk] = ne;
}

// ---------------------------------------------------------------------------
// Pass A: partition edges into buckets (packed (local<<24|src) u32).
// ---------------------------------------------------------------------------
__global__ __launch_bounds__(256) void k_passA(const unsigned* __restrict__ eiu,
                                               int* __restrict__ cursor2,
                                               unsigned* __restrict__ pairbuf,
                                               int nn, int ne) {
    __shared__ int lh[NBK_MAX];
    __shared__ int gb[NBK_MAX];
    __shared__ int nz;
    const int nbk = (nn + 255) >> 8;
    const int tid = threadIdx.x;
    const int e0 = blockIdx.x * 4096;
    for (int i = tid; i < nbk; i += 256) lh[i] = 0;
    if (tid == 0) nz = 0;
    __syncthreads();
    {
        int es = e0 + tid * 16;
        if (es >= ne) es = ne - 1;
        if (eiu[2 * (size_t)es + 1] != 0) atomicOr(&nz, 1);
    }
    __syncthreads();
    const int is64 = (nz == 0);
    unsigned pay[16];
    int bkrank[16];
#pragma unroll
    for (int j = 0; j < 16; ++j) {
        const int e = e0 + j * 256 + tid;
        bkrank[j] = -1;
        if (e < ne) {
            int src, dst;
            if (is64) {
                const long long* p = (const long long*)eiu;
                src = (int)p[e];
                dst = (int)p[(size_t)ne + e];
            } else {
                const int* p = (const int*)eiu;
                src = p[e];
                dst = p[(size_t)ne + e];
            }
            const int bk = dst >> 8;
            const int rank = atomicAdd(&lh[bk], 1);
            bkrank[j] = (bk << 16) | rank;
            pay[j] = ((unsigned)(dst & 255) << 24) | (unsigned)src;
        }
    }
    __syncthreads();
    for (int i = tid; i < nbk; i += 256) {
        const int c = lh[i];
        gb[i] = c ? atomicAdd(&cursor2[i], c) : 0;
    }
    __syncthreads();
#pragma unroll
    for (int j = 0; j < 16; ++j) {
        if (bkrank[j] >= 0) {
            const int bk = bkrank[j] >> 16, rank = bkrank[j] & 0xFFFF;
            pairbuf[gb[bk] + rank] = pay[j];
        }
    }
}

// ---------------------------------------------------------------------------
// Pass B: per bucket (256 nodes): per-node CSR within contiguous window.
// ---------------------------------------------------------------------------
__global__ __launch_bounds__(256) void k_passB(const unsigned* __restrict__ pairbuf,
                                               const int* __restrict__ bbase,
                                               int* __restrict__ off, int* __restrict__ cnt,
                                               int* __restrict__ srcbuf, int nn) {
    __shared__ int cl[256];
    __shared__ int sd[256];
    __shared__ int cur[256];
    const int tid = threadIdx.x;
    const int b = blockIdx.x;
    const int node0 = b << 8;
    const int e0 = bbase[b], e1 = bbase[b + 1];
    cl[tid] = 0;
    __syncthreads();
    for (int e = e0 + tid; e < e1; e += 256)
        atomicAdd(&cl[pairbuf[e] >> 24], 1);
    __syncthreads();
    const int v = cl[tid];
    sd[tid] = v;
    __syncthreads();
    for (int ofs = 1; ofs < 256; ofs <<= 1) {
        const int t = (tid >= ofs) ? sd[tid - ofs] : 0;
        __syncthreads();
        sd[tid] += t;
        __syncthreads();
    }
    const int ex = sd[tid] - v;
    cur[tid] = ex;
    const int node = node0 + tid;
    if (node < nn) {
        off[node] = e0 + ex;
        cnt[node] = v;
    }
    __syncthreads();
    for (int e = e0 + tid; e < e1; e += 256) {
        const unsigned p = pairbuf[e];
        const int pos = atomicAdd(&cur[p >> 24], 1);
        srcbuf[e0 + pos] = (int)(p & 0xFFFFFFu);
    }
}

// ---------------------------------------------------------------------------
// Fused: fp8 gather-mean + dual bf16 MFMA GEMM + bias + relu + BN partials.
// 512 threads = 8 waves; NB=32 nodes. GATHER: each 16-lane group owns ONE
// node; lane q accumulates feature octet [8q,8q+8) over the node's whole edge
// list, 4 edges unrolled (4 independent row loads in flight, no reduce).
// ---------------------------------------------------------------------------
__global__ __launch_bounds__(512, 4) void k_gemm(
    const float4* __restrict__ x4g, const uint2* __restrict__ xf8,
    const uint4* __restrict__ wpack, const float* __restrict__ bl,
    const int* __restrict__ off, const int* __restrict__ cnt,
    const int* __restrict__ srcbuf,
    ushort* __restrict__ hout, float* __restrict__ ssum, float* __restrict__ ssq,
    int nn)
{
    __shared__ uint4 mean4[NB * 16];
    __shared__ uint4 xls4[NB * 16];
    __shared__ float red_sum[2][DIM];
    __shared__ float red_sq[2][DIM];

    const int tid = threadIdx.x;
    const int lane = tid & 63;
    const int w = tid >> 6;
    const int base = blockIdx.x * NB;
    const int g = lane >> 4;      // group in wave -> node
    const int q = lane & 15;      // feature octet

    // ---- gather-mean: group owns node ln = w*4+g ----
    {
        const int ln = w * 4 + g;
        const int node = base + ln;
        float acc[8];
#pragma unroll
        for (int j = 0; j < 8; ++j) acc[j] = 0.f;
        uint4 xp = make_uint4(0, 0, 0, 0);

        if (node < nn) {
            // self row (f32 -> bf16 pack, 8 feats/lane)
            const float4 xa = x4g[(size_t)node * 32 + 2 * q];
            const float4 xb = x4g[(size_t)node * 32 + 2 * q + 1];
            xp.x = ((unsigned)f2bf(xa.y) << 16) | f2bf(xa.x);
            xp.y = ((unsigned)f2bf(xa.w) << 16) | f2bf(xa.z);
            xp.z = ((unsigned)f2bf(xb.y) << 16) | f2bf(xb.x);
            xp.w = ((unsigned)f2bf(xb.w) << 16) | f2bf(xb.z);

            const int o = off[node];
            const int c = cnt[node];
            int e = 0;
            for (; e + 4 <= c; e += 4) {
                const int s0 = srcbuf[o + e + 0];
                const int s1 = srcbuf[o + e + 1];
                const int s2 = srcbuf[o + e + 2];
                const int s3 = srcbuf[o + e + 3];
                const uint2 v0 = xf8[(unsigned)(s0 * 16 + q)];
                const uint2 v1 = xf8[(unsigned)(s1 * 16 + q)];
                const uint2 v2 = xf8[(unsigned)(s2 * 16 + q)];
                const uint2 v3 = xf8[(unsigned)(s3 * 16 + q)];
#pragma unroll
                for (int k = 0; k < 4; ++k) {
                    const uint2 v = (k == 0) ? v0 : (k == 1) ? v1 : (k == 2) ? v2 : v3;
                    auto p0 = __builtin_amdgcn_cvt_pk_f32_fp8(v.x, false);
                    auto p1 = __builtin_amdgcn_cvt_pk_f32_fp8(v.x, true);
                    auto p2 = __builtin_amdgcn_cvt_pk_f32_fp8(v.y, false);
                    auto p3 = __builtin_amdgcn_cvt_pk_f32_fp8(v.y, true);
                    acc[0] += p0[0]; acc[1] += p0[1]; acc[2] += p1[0]; acc[3] += p1[1];
                    acc[4] += p2[0]; acc[5] += p2[1]; acc[6] += p3[0]; acc[7] += p3[1];
                }
            }
            for (; e < c; ++e) {
                const int s = srcbuf[o + e];
                const uint2 v = xf8[(unsigned)(s * 16 + q)];
                auto p0 = __builtin_amdgcn_cvt_pk_f32_fp8(v.x, false);
                auto p1 = __builtin_amdgcn_cvt_pk_f32_fp8(v.x, true);
                auto p2 = __builtin_amdgcn_cvt_pk_f32_fp8(v.y, false);
                auto p3 = __builtin_amdgcn_cvt_pk_f32_fp8(v.y, true);
                acc[0] += p0[0]; acc[1] += p0[1]; acc[2] += p1[0]; acc[3] += p1[1];
                acc[4] += p2[0]; acc[5] += p2[1]; acc[6] += p3[0]; acc[7] += p3[1];
            }
            const float r = 1.0f / fmaxf((float)c, 1.0f);
#pragma unroll
            for (int j = 0; j < 8; ++j) acc[j] *= r;
        }

        uint4 mp;
        mp.x = ((unsigned)f2bf(acc[1]) << 16) | f2bf(acc[0]);
        mp.y = ((unsigned)f2bf(acc[3]) << 16) | f2bf(acc[2]);
        mp.z = ((unsigned)f2bf(acc[5]) << 16) | f2bf(acc[4]);
        mp.w = ((unsigned)f2bf(acc[7]) << 16) | f2bf(acc[6]);
        const int slot = q ^ (ln & 15);
        mean4[ln * 16 + slot] = mp;
        xls4[ln * 16 + slot] = xp;
    }
    __syncthreads();

    // ---- MFMA phase: wave w -> m = w&1, n-tiles nh*2 + {0,1} ----
    const int m = w & 1;
    const int nh = w >> 1;
    const int row16 = lane & 15;
    const int kgrp = lane >> 4;
    const int ln2 = m * 16 + row16;

    bf16x8 am[4], ax[4];
#pragma unroll
    for (int kk = 0; kk < 4; ++kk) {
        const int unit = (kk * 4 + kgrp) ^ row16;
        B8 va, vb;
        va.u = mean4[ln2 * 16 + unit];
        vb.u = xls4[ln2 * 16 + unit];
        am[kk] = va.s;
        ax[kk] = vb.s;
    }

    f32x4 acc[2];
#pragma unroll
    for (int j = 0; j < 2; ++j) {
        const float bv = bl[(nh * 2 + j) * 16 + row16];
        acc[j] = (f32x4){bv, bv, bv, bv};
    }

#pragma unroll
    for (int j = 0; j < 2; ++j) {
        const int nt = nh * 2 + j;
        const uint4* pl = wpack + (size_t)(nt * 4) * 64 + lane;
        const uint4* pr = wpack + (size_t)((8 + nt) * 4) * 64 + lane;
        B8 wl[4], wr[4];
#pragma unroll
        for (int kk = 0; kk < 4; ++kk) {
            wl[kk].u = pl[kk * 64];
            wr[kk].u = pr[kk * 64];
        }
#pragma unroll
        for (int kk = 0; kk < 4; ++kk)
            acc[j] = __builtin_amdgcn_mfma_f32_16x16x32_bf16(am[kk], wl[kk].s, acc[j], 0, 0, 0);
#pragma unroll
        for (int kk = 0; kk < 4; ++kk)
            acc[j] = __builtin_amdgcn_mfma_f32_16x16x32_bf16(ax[kk], wr[kk].s, acc[j], 0, 0, 0);
    }

    // ---- relu + store h (bf16) + BN partials ----
#pragma unroll
    for (int j = 0; j < 2; ++j) {
        const int feat = (nh * 2 + j) * 16 + row16;
        float s = 0.f, sq = 0.f;
#pragma unroll
        for (int r = 0; r < 4; ++r) {
            const int node = base + m * 16 + kgrp * 4 + r;
            const float v = fmaxf(acc[j][r], 0.0f);
            if (node < nn) {
                hout[(size_t)node * DIM + feat] = f2bf(v);
                s += v;
                sq += v * v;
            }
        }
        s += __shfl_xor(s, 16);
        s += __shfl_xor(s, 32);
        sq += __shfl_xor(sq, 16);
        sq += __shfl_xor(sq, 32);
        if (lane < 16) {
            red_sum[m][feat] = s;
            red_sq[m][feat] = sq;
        }
    }
    __syncthreads();
    if (tid < DIM) {
        atomicAdd(&ssum[tid], red_sum[0][tid] + red_sum[1][tid]);
        atomicAdd(&ssq[tid], red_sq[0][tid] + red_sq[1][tid]);
    }
}

// ---------------------------------------------------------------------------
// Finalize: out = x + (h - mu) * rsqrt(var+eps) * gamma + beta; h bf16.
// Grid/tile aligned with k_gemm (block j handles nodes [32j,32j+32)) so the
// hbuf tile is read on the same XCD that wrote it -> L2 hit.
// ---------------------------------------------------------------------------
__global__ __launch_bounds__(512) void k_finalize(
    const float4* __restrict__ x4, const uint4* __restrict__ h4,
    const float* __restrict__ ssum, const float* __restrict__ ssq,
    const float* __restrict__ gamma, const float* __restrict__ beta,
    float4* __restrict__ out4, int nn)
{
    const float invN = 1.0f / (float)nn;
    const int tid = threadIdx.x;
    const int node = blockIdx.x * 32 + (tid >> 4);
    const int q = tid & 15;
    if (node >= nn) return;
    const uint4 hv = h4[(size_t)node * 16 + q];
    const float4 xa = x4[(size_t)node * 32 + 2 * q];
    const float4 xb = x4[(size_t)node * 32 + 2 * q + 1];
    const float4 s4a = ((const float4*)ssum)[2 * q], s4b = ((const float4*)ssum)[2 * q + 1];
    const float4 q4a = ((const float4*)ssq)[2 * q], q4b = ((const float4*)ssq)[2 * q + 1];
    const float4 g4a = ((const float4*)gamma)[2 * q], g4b = ((const float4*)gamma)[2 * q + 1];
    const float4 b4a = ((const float4*)beta)[2 * q], b4b = ((const float4*)beta)[2 * q + 1];
    float h[8];
    h[0] = __uint_as_float(hv.x << 16);
    h[1] = __uint_as_float(hv.x & 0xffff0000u);
    h[2] = __uint_as_float(hv.y << 16);
    h[3] = __uint_as_float(hv.y & 0xffff0000u);
    h[4] = __uint_as_float(hv.z << 16);
    h[5] = __uint_as_float(hv.z & 0xffff0000u);
    h[6] = __uint_as_float(hv.w << 16);
    h[7] = __uint_as_float(hv.w & 0xffff0000u);
    float4 oa, ob;
    {
        const float mu = s4a.x * invN, rs = rsqrtf(q4a.x * invN - mu * mu + BN_EPS);
        oa.x = xa.x + (h[0] - mu) * rs * g4a.x + b4a.x;
    }
    {
        const float mu = s4a.y * invN, rs = rsqrtf(q4a.y * invN - mu * mu + BN_EPS);
        oa.y = xa.y + (h[1] - mu) * rs * g4a.y + b4a.y;
    }
    {
        const float mu = s4a.z * invN, rs = rsqrtf(q4a.z * invN - mu * mu + BN_EPS);
        oa.z = xa.z + (h[2] - mu) * rs * g4a.z + b4a.z;
    }
    {
        const float mu = s4a.w * invN, rs = rsqrtf(q4a.w * invN - mu * mu + BN_EPS);
        oa.w = xa.w + (h[3] - mu) * rs * g4a.w + b4a.w;
    }
    {
        const float mu = s4b.x * invN, rs = rsqrtf(q4b.x * invN - mu * mu + BN_EPS);
        ob.x = xb.x + (h[4] - mu) * rs * g4b.x + b4b.x;
    }
    {
        const float mu = s4b.y * invN, rs = rsqrtf(q4b.y * invN - mu * mu + BN_EPS);
        ob.y = xb.y + (h[5] - mu) * rs * g4b.y + b4b.y;
    }
    {
        const float mu = s4b.z * invN, rs = rsqrtf(q4b.z * invN - mu * mu + BN_EPS);
        ob.z = xb.z + (h[6] - mu) * rs * g4b.z + b4b.z;
    }
    {
        const float mu = s4b.w * invN, rs = rsqrtf(q4b.w * invN - mu * mu + BN_EPS);
        ob.w = xb.w + (h[7] - mu) * rs * g4b.w + b4b.w;
    }
    out4[(size_t)node * 32 + 2 * q] = oa;
    out4[(size_t)node * 32 + 2 * q + 1] = ob;
}

extern "C" void kernel_launch(void* const* d_in, const int* in_sizes, int n_in,
                              void* d_out, int out_size, void* d_ws, size_t ws_size,
                              hipStream_t stream) {
    const float* x     = (const float*)d_in[0];
    const void*  ei    = d_in[1];
    const float* Wl    = (const float*)d_in[2];
    const float* bl    = (const float*)d_in[3];
    const float* Wr    = (const float*)d_in[4];
    const float* gamma = (const float*)d_in[5];
    const float* beta  = (const float*)d_in[6];
    float* out = (float*)d_out;

    const int nn = in_sizes[0] / DIM;   // 100000
    const int ne = in_sizes[1] / 2;     // 1600000
    const int nbk = (nn + 255) >> 8;    // 391

    // workspace layout (~46 MB)
    int* ws = (int*)d_ws;
    int*   bcnt    = ws;                 // 512
    float* ssum    = (float*)(ws + 512); // 128
    float* ssq     = (float*)(ws + 640); // 128
    int*   bbase   = ws + 768;           // 512 (nbk+1)
    int*   cursor2 = ws + 1280;          // 512
    int*   cnt     = ws + 1792;          // nn
    int*   off     = cnt + nn;           // nn
    size_t pos = 1792 + 2 * (size_t)nn;
    pos = (pos + 3) & ~(size_t)3;
    uint4* wpack  = (uint4*)(ws + pos);          // 4096 uint4
    int*   srcbuf = (int*)(wpack + 4096);        // ne
    size_t p2 = (size_t)(srcbuf + ne - ws);
    p2 = (p2 + 3) & ~(size_t)3;
    uint2* xf8 = (uint2*)(ws + p2);              // nn*16 uint2 (fp8 rows)
    // union region: pairbuf (passA/passB) then hbuf (gemm/finalize)
    unsigned* pairbuf = (unsigned*)(xf8 + (size_t)nn * 16);  // ne u32
    ushort*   hbuf    = (ushort*)pairbuf;                    // nn*128 bf16

    hipMemsetAsync(d_ws, 0, 768 * sizeof(int), stream);  // bcnt + ssum + ssq

    const int PB = (nn * DIM / 8 + 255) / 256;   // 6250
    const int WB = 16;
    const int HB = (ne + 4095) / 4096;           // 391
    k_prep<<<PB + WB + HB, 256, 0, stream>>>((const float4*)x, Wl, Wr,
                                             (const unsigned*)ei, bcnt, xf8, wpack,
                                             nn, ne, PB, WB);
    k_scanb<<<1, 512, 0, stream>>>(bcnt, bbase, cursor2, nn, ne);
    k_passA<<<(ne + 4095) / 4096, 256, 0, stream>>>((const unsigned*)ei, cursor2,
                                                    pairbuf, nn, ne);
    k_passB<<<nbk, 256, 0, stream>>>(pairbuf, bbase, off, cnt, srcbuf, nn);
    const int ntile = (nn + NB - 1) / NB;        // 3125
    k_gemm<<<ntile, 512, 0, stream>>>((const float4*)x, xf8, wpack, bl, off, cnt,
                                      srcbuf, hbuf, ssum, ssq, nn);
    k_finalize<<<ntile, 512, 0, stream>>>((const float4*)x, (const uint4*)hbuf,
                                          ssum, ssq, gamma, beta, (float4*)out, nn);
}